// Round 5
// baseline (3408.812 us; speedup 1.0000x reference)
//
#include <hip/hip_runtime.h>
#include <math.h>

#define EPSB 1e-5f

typedef __attribute__((ext_vector_type(8))) short short8;
typedef __attribute__((ext_vector_type(4))) float floatx4;

__device__ inline float bf2f(unsigned short h) {
  union { unsigned int u; float f; } v; v.u = ((unsigned int)h) << 16; return v.f;
}
__device__ inline unsigned short f2bf(float f) {
  union { float f; unsigned int u; } v; v.f = f;
  unsigned int r = v.u + 0x7fffu + ((v.u >> 16) & 1u);  // RNE
  return (unsigned short)(r >> 16);
}

// ---------------- graph prep (shared by both plans) ----------------

__global__ void deg_kernel(const int* __restrict__ row, const float* __restrict__ ew,
                           float* __restrict__ deg, int E) {
  int e = blockIdx.x * blockDim.x + threadIdx.x;
  if (e < E) atomicAdd(&deg[row[e]], ew[e]);
}

__global__ void dis_kernel(float* deg, int n) {
  int i = blockIdx.x * blockDim.x + threadIdx.x;
  if (i < n) { float d = deg[i]; deg[i] = d > 0.f ? rsqrtf(d) : 0.f; }
}

__global__ void count_kernel(const int* __restrict__ col, int* __restrict__ cnt, int E) {
  int e = blockIdx.x * blockDim.x + threadIdx.x;
  if (e < E) atomicAdd(&cnt[col[e]], 1);
}

__global__ __launch_bounds__(1024) void scan_kernel(const int* __restrict__ cnt,
                                                    int* __restrict__ off, int n) {
  __shared__ int buf[1024];
  __shared__ int carry;
  int tid = threadIdx.x;
  if (tid == 0) carry = 0;
  __syncthreads();
  for (int base = 0; base < n; base += 1024) {
    int idx = base + tid;
    int v = (idx < n) ? cnt[idx] : 0;
    buf[tid] = v;
    __syncthreads();
    for (int s = 1; s < 1024; s <<= 1) {
      int t = (tid >= s) ? buf[tid - s] : 0;
      __syncthreads();
      if (tid >= s) buf[tid] += t;
      __syncthreads();
    }
    int total = buf[1023];
    if (idx < n) off[idx] = carry + buf[tid] - v;  // exclusive
    __syncthreads();
    if (tid == 0) carry += total;
    __syncthreads();
  }
  if (tid == 0) off[n] = carry;
}

__global__ void copy_kernel(const int* __restrict__ src, int* __restrict__ dst, int n) {
  int i = blockIdx.x * blockDim.x + threadIdx.x;
  if (i < n) dst[i] = src[i];
}

__global__ void fill_kernel(const int* __restrict__ row, const int* __restrict__ col,
                            const float* __restrict__ ew, const float* __restrict__ dis,
                            int* __restrict__ wptr,
                            int* __restrict__ eRow, float* __restrict__ eNorm, int E) {
  int e = blockIdx.x * blockDim.x + threadIdx.x;
  if (e < E) {
    int r = row[e], c = col[e];
    int p = atomicAdd(&wptr[c], 1);
    eRow[p] = r;
    eNorm[p] = -dis[r] * ew[e] * dis[c];
  }
}

// ================= PLAN A (bf16 + MFMA) =================

// cast x (N x 512 fp32) into Xcat cols [0,512) (ld 1536, bf16)
__global__ void cast_x_kernel(const float* __restrict__ x, unsigned short* __restrict__ xb,
                              int N) {
  int idx = blockIdx.x * blockDim.x + threadIdx.x;
  if (idx >= N * 128) return;
  int row = idx >> 7, c4 = idx & 127;
  float4 v = *reinterpret_cast<const float4*>(x + (size_t)row * 512 + c4 * 4);
  union { unsigned int u[2]; } p;
  p.u[0] = (unsigned int)f2bf(v.x) | ((unsigned int)f2bf(v.y) << 16);
  p.u[1] = (unsigned int)f2bf(v.z) | ((unsigned int)f2bf(v.w) << 16);
  *reinterpret_cast<uint2*>(xb + (size_t)row * 1536 + c4 * 4) = make_uint2(p.u[0], p.u[1]);
}

// transpose+cast weights: W[k][n] fp32 (n fastest) -> Bt[rowOff+n][k] bf16 (ld ldBt)
__global__ void wprep_kernel(const float* __restrict__ W, unsigned short* __restrict__ Bt,
                             int Ktot, int Nout, int ldBt, int rowOff) {
  int idx = blockIdx.x * blockDim.x + threadIdx.x;
  if (idx >= Ktot * Nout) return;
  int k = idx / Nout, n = idx - k * Nout;
  Bt[(size_t)(rowOff + n) * ldBt + k] = f2bf(W[idx]);
}

__global__ void bcat_kernel(const float* __restrict__ a, const float* __restrict__ b,
                            const float* __restrict__ c, float* __restrict__ dst) {
  int i = threadIdx.x;
  if (i < 100) dst[i] = a[i];
  else if (i < 200) dst[i] = b[i - 100];
  else if (i < 300) dst[i] = c[i - 200];
}

// ---- propagation v2: LDS edge staging + 4x unrolled gathers ----
// dst[v,:] = scale * sum_e norm_e * src[row_e,:] - sub[v,:]
#define PTILE 128

__device__ inline void acc8(float* a, uint4 g, float w) {
  a[0] += w * bf2f((unsigned short)(g.x & 0xffff));
  a[1] += w * bf2f((unsigned short)(g.x >> 16));
  a[2] += w * bf2f((unsigned short)(g.y & 0xffff));
  a[3] += w * bf2f((unsigned short)(g.y >> 16));
  a[4] += w * bf2f((unsigned short)(g.z & 0xffff));
  a[5] += w * bf2f((unsigned short)(g.z >> 16));
  a[6] += w * bf2f((unsigned short)(g.w & 0xffff));
  a[7] += w * bf2f((unsigned short)(g.w >> 16));
}

__global__ void prop_bf16_v2(const unsigned short* __restrict__ src, int srcLd, int D8,
                             const int* __restrict__ off, const int* __restrict__ eRow,
                             const float* __restrict__ eNorm,
                             unsigned short* __restrict__ dst, int dstLd,
                             const unsigned short* __restrict__ sub, int subLd,
                             float scale) {
  __shared__ int sR[PTILE];
  __shared__ float sW[PTILE];
  int v = blockIdx.x;
  int f8 = threadIdx.x;
  bool active = f8 < D8;
  int s = off[v], e = off[v + 1];
  float a[8] = {};
  for (int base = s; base < e; base += PTILE) {
    int cnt = min(PTILE, e - base);
    __syncthreads();
    for (int j = threadIdx.x; j < cnt; j += blockDim.x) {
      sR[j] = eRow[base + j];
      sW[j] = eNorm[base + j];
    }
    __syncthreads();
    if (active) {
      int j = 0;
      for (; j + 4 <= cnt; j += 4) {
        int r0 = sR[j], r1 = sR[j + 1], r2 = sR[j + 2], r3 = sR[j + 3];
        float w0 = sW[j], w1 = sW[j + 1], w2 = sW[j + 2], w3 = sW[j + 3];
        uint4 g0 = *reinterpret_cast<const uint4*>(src + (size_t)r0 * srcLd + f8 * 8);
        uint4 g1 = *reinterpret_cast<const uint4*>(src + (size_t)r1 * srcLd + f8 * 8);
        uint4 g2 = *reinterpret_cast<const uint4*>(src + (size_t)r2 * srcLd + f8 * 8);
        uint4 g3 = *reinterpret_cast<const uint4*>(src + (size_t)r3 * srcLd + f8 * 8);
        acc8(a, g0, w0); acc8(a, g1, w1); acc8(a, g2, w2); acc8(a, g3, w3);
      }
      for (; j < cnt; j++) {
        int r = sR[j]; float w = sW[j];
        uint4 g = *reinterpret_cast<const uint4*>(src + (size_t)r * srcLd + f8 * 8);
        acc8(a, g, w);
      }
    }
  }
  if (!active) return;
  if (sub) {
    uint4 sv = *reinterpret_cast<const uint4*>(sub + (size_t)v * subLd + f8 * 8);
    a[0] = scale * a[0] - bf2f((unsigned short)(sv.x & 0xffff));
    a[1] = scale * a[1] - bf2f((unsigned short)(sv.x >> 16));
    a[2] = scale * a[2] - bf2f((unsigned short)(sv.y & 0xffff));
    a[3] = scale * a[3] - bf2f((unsigned short)(sv.y >> 16));
    a[4] = scale * a[4] - bf2f((unsigned short)(sv.z & 0xffff));
    a[5] = scale * a[5] - bf2f((unsigned short)(sv.z >> 16));
    a[6] = scale * a[6] - bf2f((unsigned short)(sv.w & 0xffff));
    a[7] = scale * a[7] - bf2f((unsigned short)(sv.w >> 16));
  }
  uint4 o;
  o.x = (unsigned int)f2bf(a[0]) | ((unsigned int)f2bf(a[1]) << 16);
  o.y = (unsigned int)f2bf(a[2]) | ((unsigned int)f2bf(a[3]) << 16);
  o.z = (unsigned int)f2bf(a[4]) | ((unsigned int)f2bf(a[5]) << 16);
  o.w = (unsigned int)f2bf(a[6]) | ((unsigned int)f2bf(a[7]) << 16);
  *reinterpret_cast<uint4*>(dst + (size_t)v * dstLd + f8 * 8) = o;
}

// bf16 MFMA GEMM: C[m, c0+n] (+)= A[M,K](lda, bf16) * Bt[n][k] (ldb, bf16) + bias[n]
#define GBM 128
#define GBN 64
#define GBK 32
#define LPAD 8

__global__ __launch_bounds__(256) void gemm_bf16_kernel(
    const unsigned short* __restrict__ A, int lda,
    const unsigned short* __restrict__ Bt, int ldb,
    int M, int Nc, int K,
    const float* __restrict__ bias,
    unsigned short* __restrict__ Cb, float* __restrict__ Cf, int ldc, int c0,
    int accumulate) {
  __shared__ __align__(16) unsigned short As[GBM][GBK + LPAD];
  __shared__ __align__(16) unsigned short Bs[GBN][GBK + LPAD];
  int tid = threadIdx.x;
  int wave = tid >> 6, lane = tid & 63;
  int q = lane >> 4, mn = lane & 15;
  int row0 = blockIdx.y * GBM, col0 = blockIdx.x * GBN;
  floatx4 acc[2][4] = {};

  int sRow = tid >> 2;           // 0..63
  int sKoff = (tid & 3) * 8;     // 0,8,16,24

  for (int k0 = 0; k0 < K; k0 += GBK) {
#pragma unroll
    for (int p = 0; p < 2; p++) {
      int ar = sRow + p * 64;
      int gr = row0 + ar;
      uint4 av = make_uint4(0, 0, 0, 0);
      if (gr < M && (k0 + sKoff) < K)   // K multiple of 8 => full 8-elem group in-bounds
        av = *reinterpret_cast<const uint4*>(A + (size_t)gr * lda + k0 + sKoff);
      *reinterpret_cast<short8*>(&As[ar][sKoff]) = *reinterpret_cast<short8*>(&av);
    }
    {
      int gn = col0 + sRow;
      uint4 bv = make_uint4(0, 0, 0, 0);
      if (gn < Nc && (k0 + sKoff) < K)
        bv = *reinterpret_cast<const uint4*>(Bt + (size_t)gn * ldb + k0 + sKoff);
      *reinterpret_cast<short8*>(&Bs[sRow][sKoff]) = *reinterpret_cast<short8*>(&bv);
    }
    __syncthreads();

    short8 af[2], bf[4];
#pragma unroll
    for (int mi = 0; mi < 2; mi++)
      af[mi] = *reinterpret_cast<const short8*>(&As[wave * 32 + mi * 16 + mn][q * 8]);
#pragma unroll
    for (int ni = 0; ni < 4; ni++)
      bf[ni] = *reinterpret_cast<const short8*>(&Bs[ni * 16 + mn][q * 8]);
#pragma unroll
    for (int mi = 0; mi < 2; mi++)
#pragma unroll
      for (int ni = 0; ni < 4; ni++)
        acc[mi][ni] = __builtin_amdgcn_mfma_f32_16x16x32_bf16(af[mi], bf[ni], acc[mi][ni], 0, 0, 0);
    __syncthreads();
  }

  // epilogue: C/D layout col=lane&15, row=q*4+reg
#pragma unroll
  for (int mi = 0; mi < 2; mi++) {
#pragma unroll
    for (int ni = 0; ni < 4; ni++) {
      int gcol = col0 + ni * 16 + mn;
      if (gcol >= Nc) continue;
      float b = bias ? bias[gcol] : 0.f;
#pragma unroll
      for (int r = 0; r < 4; r++) {
        int grow = row0 + wave * 32 + mi * 16 + q * 4 + r;
        if (grow >= M) continue;
        float v = acc[mi][ni][r] + b;
        if (Cb) {
          Cb[(size_t)grow * ldc + c0 + gcol] = f2bf(v);
        } else {
          float* p = Cf + (size_t)grow * ldc + c0 + gcol;
          if (accumulate) v += *p;
          *p = v;
        }
      }
    }
  }
}

// BN stats over bf16 matrix (strided)
__global__ void bn_stats_bf16_kernel(const unsigned short* __restrict__ h, int ld, int C,
                                     int N, float* __restrict__ sums) {
  int c = blockIdx.x * blockDim.x + threadIdx.x;
  if (c >= C) return;
  int r0 = blockIdx.y * 256;
  int r1 = min(N, r0 + 256);
  float s = 0.f, s2 = 0.f;
  for (int r = r0; r < r1; r++) {
    float v = bf2f(h[(size_t)r * ld + c]);
    s += v; s2 += v * v;
  }
  atomicAdd(&sums[c], s);
  atomicAdd(&sums[C + c], s2);
}

__global__ void scsh_kernel(const float* __restrict__ sums, const float* __restrict__ g,
                            const float* __restrict__ beta, float invN, int C,
                            float* __restrict__ scSh) {
  int c = blockIdx.x * blockDim.x + threadIdx.x;
  if (c >= C) return;
  float mu = sums[c] * invN;
  float var = sums[C + c] * invN - mu * mu;
  float s = rsqrtf(var + EPSB) * g[c];
  scSh[c] = s;
  scSh[C + c] = beta[c] - mu * s;
}

// BN apply (+optional relu) on bf16 matrix, 8 cols/thread
__global__ void bn_apply_bf16_kernel(unsigned short* __restrict__ h, int ld, int C8, int N,
                                     const float* __restrict__ scSh, int Cfull, int relu) {
  int idx = blockIdx.x * blockDim.x + threadIdx.x;
  if (idx >= N * C8) return;
  int row = idx / C8, c8 = idx - row * C8;
  unsigned short* p = h + (size_t)row * ld + c8 * 8;
  uint4 raw = *reinterpret_cast<uint4*>(p);
  float v[8];
  v[0] = bf2f((unsigned short)(raw.x & 0xffff)); v[1] = bf2f((unsigned short)(raw.x >> 16));
  v[2] = bf2f((unsigned short)(raw.y & 0xffff)); v[3] = bf2f((unsigned short)(raw.y >> 16));
  v[4] = bf2f((unsigned short)(raw.z & 0xffff)); v[5] = bf2f((unsigned short)(raw.z >> 16));
  v[6] = bf2f((unsigned short)(raw.w & 0xffff)); v[7] = bf2f((unsigned short)(raw.w >> 16));
#pragma unroll
  for (int j = 0; j < 8; j++) {
    int c = c8 * 8 + j;
    float o = v[j] * scSh[c] + scSh[Cfull + c];
    if (relu) o = fmaxf(o, 0.f);
    v[j] = o;
  }
  uint4 o;
  o.x = (unsigned int)f2bf(v[0]) | ((unsigned int)f2bf(v[1]) << 16);
  o.y = (unsigned int)f2bf(v[2]) | ((unsigned int)f2bf(v[3]) << 16);
  o.z = (unsigned int)f2bf(v[4]) | ((unsigned int)f2bf(v[5]) << 16);
  o.w = (unsigned int)f2bf(v[6]) | ((unsigned int)f2bf(v[7]) << 16);
  *reinterpret_cast<uint4*>(p) = o;
}

// fp32 BN pieces
__global__ void bn_stats_kernel(const float* __restrict__ h, int C, int N,
                                float* __restrict__ sums) {
  int c = blockIdx.x * blockDim.x + threadIdx.x;
  if (c >= C) return;
  int r0 = blockIdx.y * 256;
  int r1 = min(N, r0 + 256);
  float s = 0.f, s2 = 0.f;
  for (int r = r0; r < r1; r++) {
    float v = h[(size_t)r * C + c];
    s += v; s2 += v * v;
  }
  atomicAdd(&sums[c], s);
  atomicAdd(&sums[C + c], s2);
}

__global__ void bn_apply_kernel(float* __restrict__ h, int C, int N,
                                const float* __restrict__ sums, const float* __restrict__ g,
                                const float* __restrict__ beta, float invN, int relu) {
  int C4 = C >> 2;
  int c4 = blockIdx.x * blockDim.x + threadIdx.x;
  if (c4 >= C4) return;
  float sc[4], sh[4];
#pragma unroll
  for (int j = 0; j < 4; j++) {
    int c = c4 * 4 + j;
    float mu = sums[c] * invN;
    float var = sums[C + c] * invN - mu * mu;
    float s = rsqrtf(var + EPSB) * g[c];
    sc[j] = s; sh[j] = beta[c] - mu * s;
  }
  int r0 = blockIdx.y * 256, r1 = min(N, r0 + 256);
  for (int r = r0; r < r1; r++) {
    float4* p = reinterpret_cast<float4*>(h + (size_t)r * C) + c4;
    float4 v = *p;
    v.x = v.x * sc[0] + sh[0]; v.y = v.y * sc[1] + sh[1];
    v.z = v.z * sc[2] + sh[2]; v.w = v.w * sc[3] + sh[3];
    if (relu) {
      v.x = fmaxf(v.x, 0.f); v.y = fmaxf(v.y, 0.f);
      v.z = fmaxf(v.z, 0.f); v.w = fmaxf(v.w, 0.f);
    }
    *p = v;
  }
}

// ---------------- final: BN2-apply fused + linear + log_softmax ----------------

__global__ __launch_bounds__(256) void final_bn_kernel(const float* __restrict__ h2,
                                                       const float* __restrict__ scSh,
                                                       const float* __restrict__ Wl,
                                                       const float* __restrict__ bl,
                                                       float* __restrict__ out, int N) {
  __shared__ float Ws[3000];
  __shared__ float S[600];
  for (int i = threadIdx.x; i < 3000; i += 256) Ws[i] = Wl[i];
  for (int i = threadIdx.x; i < 600; i += 256) S[i] = scSh[i];
  __syncthreads();
  int r = blockIdx.x * blockDim.x + threadIdx.x;
  if (r >= N) return;
  float acc[10];
#pragma unroll
  for (int c = 0; c < 10; c++) acc[c] = bl[c];
  const float* hr = h2 + (size_t)r * 300;
  for (int k = 0; k < 300; k++) {
    float x = hr[k] * S[k] + S[300 + k];
#pragma unroll
    for (int c = 0; c < 10; c++) acc[c] += x * Ws[k * 10 + c];
  }
  float mx = acc[0];
#pragma unroll
  for (int c = 1; c < 10; c++) mx = fmaxf(mx, acc[c]);
  float se = 0.f;
#pragma unroll
  for (int c = 0; c < 10; c++) se += expf(acc[c] - mx);
  float lz = mx + logf(se);
#pragma unroll
  for (int c = 0; c < 10; c++) out[(size_t)r * 10 + c] = acc[c] - lz;
}

// plain final for Plan B
__global__ __launch_bounds__(256) void final_kernel(const float* __restrict__ h2,
                                                    const float* __restrict__ Wl,
                                                    const float* __restrict__ bl,
                                                    float* __restrict__ out, int N) {
  __shared__ float Ws[3000];
  for (int i = threadIdx.x; i < 3000; i += 256) Ws[i] = Wl[i];
  __syncthreads();
  int r = blockIdx.x * blockDim.x + threadIdx.x;
  if (r >= N) return;
  float acc[10];
#pragma unroll
  for (int c = 0; c < 10; c++) acc[c] = bl[c];
  const float* hr = h2 + (size_t)r * 300;
  for (int k = 0; k < 300; k++) {
    float x = hr[k];
#pragma unroll
    for (int c = 0; c < 10; c++) acc[c] += x * Ws[k * 10 + c];
  }
  float mx = acc[0];
#pragma unroll
  for (int c = 1; c < 10; c++) mx = fmaxf(mx, acc[c]);
  float se = 0.f;
#pragma unroll
  for (int c = 0; c < 10; c++) se += expf(acc[c] - mx);
  float lz = mx + logf(se);
#pragma unroll
  for (int c = 0; c < 10; c++) out[(size_t)r * 10 + c] = acc[c] - lz;
}

// ================= PLAN B (fp32 fallback, known-good) =================

__global__ void prop_kernel(const float* __restrict__ src, int srcLd4, int D4,
                            const int* __restrict__ off, const int* __restrict__ eRow,
                            const float* __restrict__ eNorm,
                            float* __restrict__ dst, int dstLd4,
                            const float* __restrict__ sub, int subLd4, float scale) {
  int v = blockIdx.x;
  int f4 = threadIdx.x;
  if (f4 >= D4) return;
  int s = off[v], e = off[v + 1];
  float ax = 0.f, ay = 0.f, az = 0.f, aw = 0.f;
  for (int i = s; i < e; i++) {
    int r = eRow[i];
    float w = eNorm[i];
    const float4 hv = *reinterpret_cast<const float4*>(src + ((size_t)r * srcLd4 + f4) * 4);
    ax += w * hv.x; ay += w * hv.y; az += w * hv.z; aw += w * hv.w;
  }
  float4 o;
  if (sub) {
    const float4 sv = *reinterpret_cast<const float4*>(sub + ((size_t)v * subLd4 + f4) * 4);
    o.x = scale * ax - sv.x; o.y = scale * ay - sv.y;
    o.z = scale * az - sv.z; o.w = scale * aw - sv.w;
  } else {
    o.x = ax; o.y = ay; o.z = az; o.w = aw;
  }
  *reinterpret_cast<float4*>(dst + ((size_t)v * dstLd4 + f4) * 4) = o;
}

#define BM 64
#define BN 64
#define BK 16

__global__ __launch_bounds__(256) void gemm_kernel(
    const float* __restrict__ A, int lda,
    const float* __restrict__ B, int ldb,
    float* __restrict__ C, int ldc, int c0,
    int M, int Nc, int K,
    const float* __restrict__ bias, int accumulate) {
  __shared__ float As[BK][BM + 4];
  __shared__ float Bs[BK][BN + 4];
  int tid = threadIdx.x;
  int tx = tid & 15, ty = tid >> 4;
  int row0 = blockIdx.y * BM, col0 = blockIdx.x * BN;
  float acc[4][4] = {};
  int aM = tid >> 2;
  int aK = (tid & 3) << 2;
  int bK = tid >> 4;
  int bN = (tid & 15) << 2;
  for (int k0 = 0; k0 < K; k0 += BK) {
    float4 av = make_float4(0.f, 0.f, 0.f, 0.f);
    int ar = row0 + aM;
    if (ar < M && k0 + aK < K)
      av = *reinterpret_cast<const float4*>(A + (size_t)ar * lda + k0 + aK);
    As[aK + 0][aM] = av.x; As[aK + 1][aM] = av.y;
    As[aK + 2][aM] = av.z; As[aK + 3][aM] = av.w;
    float4 bv = make_float4(0.f, 0.f, 0.f, 0.f);
    int bc = col0 + bN;
    if (bc < Nc && k0 + bK < K)
      bv = *reinterpret_cast<const float4*>(B + (size_t)(k0 + bK) * ldb + bc);
    Bs[bK][bN + 0] = bv.x; Bs[bK][bN + 1] = bv.y;
    Bs[bK][bN + 2] = bv.z; Bs[bK][bN + 3] = bv.w;
    __syncthreads();
#pragma unroll
    for (int k = 0; k < BK; k++) {
      float a0 = As[k][ty * 4 + 0], a1 = As[k][ty * 4 + 1];
      float a2 = As[k][ty * 4 + 2], a3 = As[k][ty * 4 + 3];
      float b0 = Bs[k][tx * 4 + 0], b1 = Bs[k][tx * 4 + 1];
      float b2 = Bs[k][tx * 4 + 2], b3 = Bs[k][tx * 4 + 3];
      acc[0][0] += a0 * b0; acc[0][1] += a0 * b1; acc[0][2] += a0 * b2; acc[0][3] += a0 * b3;
      acc[1][0] += a1 * b0; acc[1][1] += a1 * b1; acc[1][2] += a1 * b2; acc[1][3] += a1 * b3;
      acc[2][0] += a2 * b0; acc[2][1] += a2 * b1; acc[2][2] += a2 * b2; acc[2][3] += a2 * b3;
      acc[3][0] += a3 * b0; acc[3][1] += a3 * b1; acc[3][2] += a3 * b2; acc[3][3] += a3 * b3;
    }
    __syncthreads();
  }
#pragma unroll
  for (int i = 0; i < 4; i++) {
    int r = row0 + ty * 4 + i;
    if (r >= M) continue;
#pragma unroll
    for (int j = 0; j < 4; j++) {
      int c = col0 + tx * 4 + j;
      if (c >= Nc) continue;
      float v = acc[i][j];
      if (bias) v += bias[c];
      float* p = C + (size_t)r * ldc + c0 + c;
      if (accumulate) *p += v; else *p = v;
    }
  }
}

// ---------------- launch ----------------

extern "C" void kernel_launch(void* const* d_in, const int* in_sizes, int n_in,
                              void* d_out, int out_size, void* d_ws, size_t ws_size,
                              hipStream_t stream) {
  const float* x   = (const float*)d_in[0];
  const int*   ei  = (const int*)d_in[1];
  const float* ew  = (const float*)d_in[2];
  const float* W1a = (const float*)d_in[3];
  const float* b1a = (const float*)d_in[4];
  const float* W1b = (const float*)d_in[5];
  const float* b1b = (const float*)d_in[6];
  const float* W1c = (const float*)d_in[7];
  const float* b1c = (const float*)d_in[8];
  const float* g1  = (const float*)d_in[9];
  const float* be1 = (const float*)d_in[10];
  const float* W2a = (const float*)d_in[11];
  const float* b2a = (const float*)d_in[12];
  const float* W2b = (const float*)d_in[13];
  const float* b2b = (const float*)d_in[14];
  const float* W2c = (const float*)d_in[15];
  const float* b2c = (const float*)d_in[16];
  const float* g2  = (const float*)d_in[17];
  const float* be2 = (const float*)d_in[18];
  const float* Wl  = (const float*)d_in[19];
  const float* bl  = (const float*)d_in[20];
  float* out = (float*)d_out;

  const int N = in_sizes[0] / 512;
  const int E = in_sizes[1] / 2;
  const int* row = ei;
  const int* col = ei + E;
  (void)n_in; (void)out_size;

  int eb = (E + 255) / 256;
  int nb = (N + 255) / 256;

  // ---- common prefix layout ----
  char* ws = (char*)d_ws;
  size_t o = 0;
  int*   eRow  = (int*)(ws + o);   o += (size_t)E * 4;
  float* eNorm = (float*)(ws + o); o += (size_t)E * 4;
  float* dis   = (float*)(ws + o); o += (size_t)N * 4;
  int*   cnt   = (int*)(ws + o);   o += (size_t)N * 4;
  int*   off   = (int*)(ws + o);   o += (size_t)(N + 4) * 4;
  int*   wptr  = (int*)(ws + o);   o += (size_t)N * 4;
  float* sums  = (float*)(ws + o); o += 2400 * 4;
  float* scSh  = (float*)(ws + o); o += 2400 * 4;
  float* bcat  = (float*)(ws + o); o += 304 * 4;
  o = (o + 255) & ~(size_t)255;
  size_t oCommon = o;

  // ---- plan A layout (~351 MB) ----
  size_t oA = oCommon;
  unsigned short* Bt1a = (unsigned short*)(ws + oA); oA += (size_t)400 * 512 * 2;
  unsigned short* Bt1b = (unsigned short*)(ws + oA); oA += (size_t)400 * 1024 * 2;
  unsigned short* Bt1c = (unsigned short*)(ws + oA); oA += (size_t)400 * 1536 * 2;
  unsigned short* Bt2cat0 = (unsigned short*)(ws + oA); oA += (size_t)300 * 1200 * 2;
  unsigned short* Bt2cat1 = (unsigned short*)(ws + oA); oA += (size_t)200 * 1200 * 2;
  unsigned short* Bt2c2   = (unsigned short*)(ws + oA); oA += (size_t)100 * 1200 * 2;
  oA = (oA + 255) & ~(size_t)255;
  unsigned short* h1n = (unsigned short*)(ws + oA); oA += (size_t)N * 1200 * 2;  // h1 / later R
  oA = (oA + 255) & ~(size_t)255;
  float* h2f = (float*)(ws + oA); oA += (size_t)N * 300 * 4;
  oA = (oA + 255) & ~(size_t)255;
  // region X: Xcat (N x 1536 bf16) in phase 1; Q1 (N x 1200 bf16) in phase 2
  unsigned short* Xcat = (unsigned short*)(ws + oA); oA += (size_t)N * 1536 * 2;
  unsigned short* Q1 = Xcat;

  bool planA = (ws_size >= oA);

  // ---- graph prep (both plans) ----
  hipMemsetAsync(dis, 0, (size_t)N * 4, stream);
  hipMemsetAsync(cnt, 0, (size_t)N * 4, stream);
  deg_kernel<<<eb, 256, 0, stream>>>(row, ew, dis, E);
  dis_kernel<<<nb, 256, 0, stream>>>(dis, N);
  count_kernel<<<eb, 256, 0, stream>>>(col, cnt, E);
  scan_kernel<<<1, 1024, 0, stream>>>(cnt, off, N);
  copy_kernel<<<nb, 256, 0, stream>>>(off, wptr, N);
  fill_kernel<<<eb, 256, 0, stream>>>(row, col, ew, dis, wptr, eRow, eNorm, E);

  if (planA) {
    // weight prep + x cast
    wprep_kernel<<<(400 * 512 + 255) / 256, 256, 0, stream>>>(W1a, Bt1a, 512, 400, 512, 0);
    wprep_kernel<<<(400 * 1024 + 255) / 256, 256, 0, stream>>>(W1b, Bt1b, 1024, 400, 1024, 0);
    wprep_kernel<<<(400 * 1536 + 255) / 256, 256, 0, stream>>>(W1c, Bt1c, 1536, 400, 1536, 0);
    // layer-2 concatenated-output weights
    wprep_kernel<<<(100 * 1200 + 255) / 256, 256, 0, stream>>>(W2a, Bt2cat0, 1200, 100, 1200, 0);
    wprep_kernel<<<(100 * 1200 + 255) / 256, 256, 0, stream>>>(W2b, Bt2cat0, 1200, 100, 1200, 100);
    wprep_kernel<<<(100 * 1200 + 255) / 256, 256, 0, stream>>>(W2c, Bt2cat0, 1200, 100, 1200, 200);
    wprep_kernel<<<(100 * 1200 + 255) / 256, 256, 0, stream>>>(W2b + 1200 * 100, Bt2cat1, 1200, 100, 1200, 0);
    wprep_kernel<<<(100 * 1200 + 255) / 256, 256, 0, stream>>>(W2c + 1200 * 100, Bt2cat1, 1200, 100, 1200, 100);
    wprep_kernel<<<(100 * 1200 + 255) / 256, 256, 0, stream>>>(W2c + 2 * 1200 * 100, Bt2c2, 1200, 100, 1200, 0);
    bcat_kernel<<<1, 320, 0, stream>>>(b2a, b2b, b2c, bcat);
    cast_x_kernel<<<(N * 128 + 255) / 256, 256, 0, stream>>>(x, Xcat, N);

    // layer-1 props into Xcat: P1 = prop(x), P2 = 2*prop(P1) - x
    prop_bf16_v2<<<N, 64, 0, stream>>>(Xcat, 1536, 64, off, eRow, eNorm,
                                       Xcat + 512, 1536, nullptr, 0, 1.f);
    prop_bf16_v2<<<N, 64, 0, stream>>>(Xcat + 512, 1536, 64, off, eRow, eNorm,
                                       Xcat + 1024, 1536, Xcat, 1536, 2.f);

    // layer-1 GEMMs -> h1n (bf16, ld 1200)
    dim3 gA((400 + GBN - 1) / GBN, (N + GBM - 1) / GBM);
    gemm_bf16_kernel<<<gA, 256, 0, stream>>>(Xcat, 1536, Bt1a, 512, N, 400, 512,
                                             b1a, h1n, nullptr, 1200, 0, 0);
    gemm_bf16_kernel<<<gA, 256, 0, stream>>>(Xcat, 1536, Bt1b, 1024, N, 400, 1024,
                                             b1b, h1n, nullptr, 1200, 400, 0);
    gemm_bf16_kernel<<<gA, 256, 0, stream>>>(Xcat, 1536, Bt1c, 1536, N, 400, 1536,
                                             b1c, h1n, nullptr, 1200, 800, 0);

    // BN1 + ReLU on h1n
    hipMemsetAsync(sums, 0, 2400 * 4, stream);
    dim3 s1g((1200 + 255) / 256, (N + 255) / 256);
    bn_stats_bf16_kernel<<<s1g, 256, 0, stream>>>(h1n, 1200, 1200, N, sums);
    scsh_kernel<<<(1200 + 255) / 256, 256, 0, stream>>>(sums, g1, be1, 1.f / (float)N, 1200, scSh);
    bn_apply_bf16_kernel<<<((size_t)N * 150 + 255) / 256, 256, 0, stream>>>(
        h1n, 1200, 150, N, scSh, 1200, 1);

    // layer-2: fused GEMM over concatenated outputs [h1·W2a | h1·W2b0 | h1·W2c0]
    dim3 gB0((300 + GBN - 1) / GBN, (N + GBM - 1) / GBM);
    gemm_bf16_kernel<<<gB0, 256, 0, stream>>>(h1n, 1200, Bt2cat0, 1200, N, 300, 1200,
                                              bcat, nullptr, h2f, 300, 0, 0);

    // Q1 = prop(h1n)  (Xcat dead -> region is Q1)
    prop_bf16_v2<<<N, 192, 0, stream>>>(h1n, 1200, 150, off, eRow, eNorm,
                                        Q1, 1200, nullptr, 0, 1.f);
    dim3 gB1((200 + GBN - 1) / GBN, (N + GBM - 1) / GBM);
    gemm_bf16_kernel<<<gB1, 256, 0, stream>>>(Q1, 1200, Bt2cat1, 1200, N, 200, 1200,
                                              nullptr, nullptr, h2f, 300, 100, 1);

    // R = 2*prop(Q1) - h1n, in place into h1n
    prop_bf16_v2<<<N, 192, 0, stream>>>(Q1, 1200, 150, off, eRow, eNorm,
                                        h1n, 1200, h1n, 1200, 2.f);
    dim3 gB2((100 + GBN - 1) / GBN, (N + GBM - 1) / GBM);
    gemm_bf16_kernel<<<gB2, 256, 0, stream>>>(h1n, 1200, Bt2c2, 1200, N, 100, 1200,
                                              nullptr, nullptr, h2f, 300, 200, 1);

    // BN2 stats -> scSh; apply fused into final
    hipMemsetAsync(sums, 0, 2400 * 4, stream);
    dim3 s2g((300 + 255) / 256, (N + 255) / 256);
    bn_stats_kernel<<<s2g, 256, 0, stream>>>(h2f, 300, N, sums);
    scsh_kernel<<<(300 + 255) / 256, 256, 0, stream>>>(sums, g2, be2, 1.f / (float)N, 300, scSh);
    final_bn_kernel<<<nb, 256, 0, stream>>>(h2f, scSh, Wl, bl, out, N);
    return;
  }

  // ================= PLAN B (fp32 fallback) =================
  size_t oB = oCommon;
  float* h2 = (float*)(ws + oB); oB += (size_t)N * 300 * 4;
  oB = (oB + 255) & ~(size_t)255;
  float* h1 = (float*)(ws + oB); oB += (size_t)N * 1200 * 4;
  oB = (oB + 255) & ~(size_t)255;
  size_t avail = (ws_size > oB) ? (ws_size - oB) : 0;
  int C1 = 64;
  { const int opts[4] = {512, 256, 128, 64};
    for (int i = 0; i < 4; i++)
      if ((size_t)2 * N * opts[i] * 4 <= avail) { C1 = opts[i]; break; } }
  int C2 = 100;
  { const int opts[6] = {1200, 600, 400, 300, 200, 100};
    for (int i = 0; i < 6; i++)
      if ((size_t)2 * N * opts[i] * 4 <= avail) { C2 = opts[i]; break; } }
  int maxC = C1 > C2 ? C1 : C2;
  float* S1 = (float*)(ws + oB);
  float* S2 = S1 + (size_t)N * maxC;

  dim3 g1d((400 + BN - 1) / BN, (N + BM - 1) / BM);
  gemm_kernel<<<g1d, 256, 0, stream>>>(x, 512, W1a, 400, h1, 1200, 0,   N, 400, 512, b1a, 0);
  gemm_kernel<<<g1d, 256, 0, stream>>>(x, 512, W1b, 400, h1, 1200, 400, N, 400, 512, b1b, 0);
  gemm_kernel<<<g1d, 256, 0, stream>>>(x, 512, W1c, 400, h1, 1200, 800, N, 400, 512, b1c, 0);
  for (int c = 0; c < 512; c += C1) {
    int D4 = C1 / 4;
    int bt = ((D4 + 63) / 64) * 64;
    prop_kernel<<<N, bt, 0, stream>>>(x + c, 128, D4, off, eRow, eNorm, S1, D4, nullptr, 0, 1.f);
    gemm_kernel<<<g1d, 256, 0, stream>>>(S1, C1, W1b + (size_t)(512 + c) * 400, 400, h1, 1200, 400, N, 400, C1, nullptr, 1);
    gemm_kernel<<<g1d, 256, 0, stream>>>(S1, C1, W1c + (size_t)(512 + c) * 400, 400, h1, 1200, 800, N, 400, C1, nullptr, 1);
    prop_kernel<<<N, bt, 0, stream>>>(S1, D4, D4, off, eRow, eNorm, S2, D4, x + c, 128, 2.f);
    gemm_kernel<<<g1d, 256, 0, stream>>>(S2, C1, W1c + (size_t)(2 * 512 + c) * 400, 400, h1, 1200, 800, N, 400, C1, nullptr, 1);
  }

  hipMemsetAsync(sums, 0, 2400 * 4, stream);
  dim3 s1g((1200 + 255) / 256, (N + 255) / 256);
  bn_stats_kernel<<<s1g, 256, 0, stream>>>(h1, 1200, N, sums);
  dim3 a1g((300 + 63) / 64, (N + 255) / 256);
  bn_apply_kernel<<<a1g, 64, 0, stream>>>(h1, 1200, N, sums, g1, be1, 1.f / (float)N, 1);

  dim3 g2d((100 + BN - 1) / BN, (N + BM - 1) / BM);
  gemm_kernel<<<g2d, 256, 0, stream>>>(h1, 1200, W2a, 100, h2, 300, 0,   N, 100, 1200, b2a, 0);
  gemm_kernel<<<g2d, 256, 0, stream>>>(h1, 1200, W2b, 100, h2, 300, 100, N, 100, 1200, b2b, 0);
  gemm_kernel<<<g2d, 256, 0, stream>>>(h1, 1200, W2c, 100, h2, 300, 200, N, 100, 1200, b2c, 0);
  for (int c = 0; c < 1200; c += C2) {
    int D4 = C2 / 4;
    int bt = ((D4 + 63) / 64) * 64;
    prop_kernel<<<N, bt, 0, stream>>>(h1 + c, 300, D4, off, eRow, eNorm, S1, D4, nullptr, 0, 1.f);
    gemm_kernel<<<g2d, 256, 0, stream>>>(S1, C2, W2b + (size_t)(1200 + c) * 100, 100, h2, 300, 100, N, 100, C2, nullptr, 1);
    gemm_kernel<<<g2d, 256, 0, stream>>>(S1, C2, W2c + (size_t)(1200 + c) * 100, 100, h2, 300, 200, N, 100, C2, nullptr, 1);
    prop_kernel<<<N, bt, 0, stream>>>(S1, D4, D4, off, eRow, eNorm, S2, D4, h1 + c, 300, 2.f);
    gemm_kernel<<<g2d, 256, 0, stream>>>(S2, C2, W2c + (size_t)(2 * 1200 + c) * 100, 100, h2, 300, 200, N, 100, C2, nullptr, 1);
  }

  hipMemsetAsync(sums, 0, 2400 * 4, stream);
  dim3 s2g((300 + 255) / 256, (N + 255) / 256);
  bn_stats_kernel<<<s2g, 256, 0, stream>>>(h2, 300, N, sums);
  dim3 a2g((75 + 63) / 64, (N + 255) / 256);
  bn_apply_kernel<<<a2g, 64, 0, stream>>>(h2, 300, N, sums, g2, be2, 1.f / (float)N, 0);

  final_kernel<<<nb, 256, 0, stream>>>(h2, Wl, bl, out, N);
}

// Round 6
// 2388.369 us; speedup vs baseline: 1.4273x; 1.4273x over previous
//
#include <hip/hip_runtime.h>
#include <math.h>

#define EPSB 1e-5f

typedef __attribute__((ext_vector_type(8))) short short8;
typedef __attribute__((ext_vector_type(4))) float floatx4;

__device__ inline float bf2f(unsigned short h) {
  union { unsigned int u; float f; } v; v.u = ((unsigned int)h) << 16; return v.f;
}
__device__ inline unsigned short f2bf(float f) {
  union { float f; unsigned int u; } v; v.f = f;
  unsigned int r = v.u + 0x7fffu + ((v.u >> 16) & 1u);  // RNE
  return (unsigned short)(r >> 16);
}

// ---------------- graph prep (shared by both plans) ----------------

__global__ void deg_kernel(const int* __restrict__ row, const float* __restrict__ ew,
                           float* __restrict__ deg, int E) {
  int e = blockIdx.x * blockDim.x + threadIdx.x;
  if (e < E) atomicAdd(&deg[row[e]], ew[e]);
}

__global__ void dis_kernel(float* deg, int n) {
  int i = blockIdx.x * blockDim.x + threadIdx.x;
  if (i < n) { float d = deg[i]; deg[i] = d > 0.f ? rsqrtf(d) : 0.f; }
}

__global__ void count_kernel(const int* __restrict__ col, int* __restrict__ cnt, int E) {
  int e = blockIdx.x * blockDim.x + threadIdx.x;
  if (e < E) atomicAdd(&cnt[col[e]], 1);
}

__global__ __launch_bounds__(1024) void scan_kernel(const int* __restrict__ cnt,
                                                    int* __restrict__ off, int n) {
  __shared__ int buf[1024];
  __shared__ int carry;
  int tid = threadIdx.x;
  if (tid == 0) carry = 0;
  __syncthreads();
  for (int base = 0; base < n; base += 1024) {
    int idx = base + tid;
    int v = (idx < n) ? cnt[idx] : 0;
    buf[tid] = v;
    __syncthreads();
    for (int s = 1; s < 1024; s <<= 1) {
      int t = (tid >= s) ? buf[tid - s] : 0;
      __syncthreads();
      if (tid >= s) buf[tid] += t;
      __syncthreads();
    }
    int total = buf[1023];
    if (idx < n) off[idx] = carry + buf[tid] - v;  // exclusive
    __syncthreads();
    if (tid == 0) carry += total;
    __syncthreads();
  }
  if (tid == 0) off[n] = carry;
}

__global__ void copy_kernel(const int* __restrict__ src, int* __restrict__ dst, int n) {
  int i = blockIdx.x * blockDim.x + threadIdx.x;
  if (i < n) dst[i] = src[i];
}

__global__ void fill_kernel(const int* __restrict__ row, const int* __restrict__ col,
                            const float* __restrict__ ew, const float* __restrict__ dis,
                            int* __restrict__ wptr,
                            int* __restrict__ eRow, float* __restrict__ eNorm, int E) {
  int e = blockIdx.x * blockDim.x + threadIdx.x;
  if (e < E) {
    int r = row[e], c = col[e];
    int p = atomicAdd(&wptr[c], 1);
    eRow[p] = r;
    eNorm[p] = -dis[r] * ew[e] * dis[c];
  }
}

// ================= PLAN A (bf16 + MFMA) =================

// cast x (N x 512 fp32) into Xcat cols [0,512) (ld 1536, bf16)
__global__ void cast_x_kernel(const float* __restrict__ x, unsigned short* __restrict__ xb,
                              int N) {
  int idx = blockIdx.x * blockDim.x + threadIdx.x;
  if (idx >= N * 128) return;
  int row = idx >> 7, c4 = idx & 127;
  float4 v = *reinterpret_cast<const float4*>(x + (size_t)row * 512 + c4 * 4);
  union { unsigned int u[2]; } p;
  p.u[0] = (unsigned int)f2bf(v.x) | ((unsigned int)f2bf(v.y) << 16);
  p.u[1] = (unsigned int)f2bf(v.z) | ((unsigned int)f2bf(v.w) << 16);
  *reinterpret_cast<uint2*>(xb + (size_t)row * 1536 + c4 * 4) = make_uint2(p.u[0], p.u[1]);
}

// transpose+cast weights: W[k][n] fp32 (n fastest) -> Bt[rowOff+n][k] bf16 (ld ldBt)
__global__ void wprep_kernel(const float* __restrict__ W, unsigned short* __restrict__ Bt,
                             int Ktot, int Nout, int ldBt, int rowOff) {
  int idx = blockIdx.x * blockDim.x + threadIdx.x;
  if (idx >= Ktot * Nout) return;
  int k = idx / Nout, n = idx - k * Nout;
  Bt[(size_t)(rowOff + n) * ldBt + k] = f2bf(W[idx]);
}

__global__ void bcat_kernel(const float* __restrict__ a, const float* __restrict__ b,
                            const float* __restrict__ c, float* __restrict__ dst) {
  int i = threadIdx.x;
  if (i < 100) dst[i] = a[i];
  else if (i < 200) dst[i] = b[i - 100];
  else if (i < 300) dst[i] = c[i - 200];
}

// ---- propagation v1 (simple, high-occupancy) ----
// dst[v,:] = scale * sum_e norm_e * src[row_e,:] - sub[v,:]
__global__ void prop_bf16_kernel(const unsigned short* __restrict__ src, int srcLd, int D8,
                                 const int* __restrict__ off, const int* __restrict__ eRow,
                                 const float* __restrict__ eNorm,
                                 unsigned short* __restrict__ dst, int dstLd,
                                 const unsigned short* __restrict__ sub, int subLd,
                                 float scale) {
  int v = blockIdx.x;
  int f8 = threadIdx.x;
  if (f8 >= D8) return;
  int s = off[v], e = off[v + 1];
  float a[8] = {};
  for (int i = s; i < e; i++) {
    int r = eRow[i];
    float w = eNorm[i];
    uint4 raw = *reinterpret_cast<const uint4*>(src + (size_t)r * srcLd + f8 * 8);
    a[0] += w * bf2f((unsigned short)(raw.x & 0xffff));
    a[1] += w * bf2f((unsigned short)(raw.x >> 16));
    a[2] += w * bf2f((unsigned short)(raw.y & 0xffff));
    a[3] += w * bf2f((unsigned short)(raw.y >> 16));
    a[4] += w * bf2f((unsigned short)(raw.z & 0xffff));
    a[5] += w * bf2f((unsigned short)(raw.z >> 16));
    a[6] += w * bf2f((unsigned short)(raw.w & 0xffff));
    a[7] += w * bf2f((unsigned short)(raw.w >> 16));
  }
  if (sub) {
    uint4 sv = *reinterpret_cast<const uint4*>(sub + (size_t)v * subLd + f8 * 8);
    a[0] = scale * a[0] - bf2f((unsigned short)(sv.x & 0xffff));
    a[1] = scale * a[1] - bf2f((unsigned short)(sv.x >> 16));
    a[2] = scale * a[2] - bf2f((unsigned short)(sv.y & 0xffff));
    a[3] = scale * a[3] - bf2f((unsigned short)(sv.y >> 16));
    a[4] = scale * a[4] - bf2f((unsigned short)(sv.z & 0xffff));
    a[5] = scale * a[5] - bf2f((unsigned short)(sv.z >> 16));
    a[6] = scale * a[6] - bf2f((unsigned short)(sv.w & 0xffff));
    a[7] = scale * a[7] - bf2f((unsigned short)(sv.w >> 16));
  }
  uint4 o;
  o.x = (unsigned int)f2bf(a[0]) | ((unsigned int)f2bf(a[1]) << 16);
  o.y = (unsigned int)f2bf(a[2]) | ((unsigned int)f2bf(a[3]) << 16);
  o.z = (unsigned int)f2bf(a[4]) | ((unsigned int)f2bf(a[5]) << 16);
  o.w = (unsigned int)f2bf(a[6]) | ((unsigned int)f2bf(a[7]) << 16);
  *reinterpret_cast<uint4*>(dst + (size_t)v * dstLd + f8 * 8) = o;
}

// ---- commuted layer-2 props ----
// Zcat: N x 304 bf16 = [Z1 = h1n*[W2b1|W2c1] (200) | Z2 = h1n*W2c2 (100) | zeros (4)]
// prop_z: acc = sum_e norm * Zcat[row_e]; groups 0..24 (cols 0:200): h2f[v,100+c] += acc
//         groups 25..37 (cols 200:304): U1[v, c-200] = bf16(acc)   (U1 = L*Z2)
__global__ void prop_z_kernel(const unsigned short* __restrict__ Zcat,
                              const int* __restrict__ off, const int* __restrict__ eRow,
                              const float* __restrict__ eNorm,
                              float* __restrict__ h2f, unsigned short* __restrict__ U1) {
  int v = blockIdx.x;
  int f8 = threadIdx.x;
  if (f8 >= 38) return;
  int s = off[v], e = off[v + 1];
  float a[8] = {};
  for (int i = s; i < e; i++) {
    int r = eRow[i];
    float w = eNorm[i];
    uint4 raw = *reinterpret_cast<const uint4*>(Zcat + (size_t)r * 304 + f8 * 8);
    a[0] += w * bf2f((unsigned short)(raw.x & 0xffff));
    a[1] += w * bf2f((unsigned short)(raw.x >> 16));
    a[2] += w * bf2f((unsigned short)(raw.y & 0xffff));
    a[3] += w * bf2f((unsigned short)(raw.y >> 16));
    a[4] += w * bf2f((unsigned short)(raw.z & 0xffff));
    a[5] += w * bf2f((unsigned short)(raw.z >> 16));
    a[6] += w * bf2f((unsigned short)(raw.w & 0xffff));
    a[7] += w * bf2f((unsigned short)(raw.w >> 16));
  }
  if (f8 < 25) {
    float* p = h2f + (size_t)v * 300 + 100 + f8 * 8;
#pragma unroll
    for (int j = 0; j < 8; j++) p[j] += a[j];
  } else {
    uint4 o;
    o.x = (unsigned int)f2bf(a[0]) | ((unsigned int)f2bf(a[1]) << 16);
    o.y = (unsigned int)f2bf(a[2]) | ((unsigned int)f2bf(a[3]) << 16);
    o.z = (unsigned int)f2bf(a[4]) | ((unsigned int)f2bf(a[5]) << 16);
    o.w = (unsigned int)f2bf(a[6]) | ((unsigned int)f2bf(a[7]) << 16);
    *reinterpret_cast<uint4*>(U1 + (size_t)v * 104 + (f8 - 25) * 8) = o;
  }
}

// prop_u: acc = sum_e norm * U1[row_e]  (U1 = L*Z2, 104 wide, cols>=100 are zero)
// h2f[v,200+c] += 2*acc - Z2[v,c]  for c < 100
__global__ void prop_u_kernel(const unsigned short* __restrict__ U1,
                              const int* __restrict__ off, const int* __restrict__ eRow,
                              const float* __restrict__ eNorm,
                              const unsigned short* __restrict__ Zcat,
                              float* __restrict__ h2f) {
  int v = blockIdx.x;
  int f8 = threadIdx.x;
  if (f8 >= 13) return;
  int s = off[v], e = off[v + 1];
  float a[8] = {};
  for (int i = s; i < e; i++) {
    int r = eRow[i];
    float w = eNorm[i];
    uint4 raw = *reinterpret_cast<const uint4*>(U1 + (size_t)r * 104 + f8 * 8);
    a[0] += w * bf2f((unsigned short)(raw.x & 0xffff));
    a[1] += w * bf2f((unsigned short)(raw.x >> 16));
    a[2] += w * bf2f((unsigned short)(raw.y & 0xffff));
    a[3] += w * bf2f((unsigned short)(raw.y >> 16));
    a[4] += w * bf2f((unsigned short)(raw.z & 0xffff));
    a[5] += w * bf2f((unsigned short)(raw.z >> 16));
    a[6] += w * bf2f((unsigned short)(raw.w & 0xffff));
    a[7] += w * bf2f((unsigned short)(raw.w >> 16));
  }
  const unsigned short* z2 = Zcat + (size_t)v * 304 + 200;
  float* p = h2f + (size_t)v * 300 + 200;
#pragma unroll
  for (int j = 0; j < 8; j++) {
    int c = f8 * 8 + j;
    if (c < 100) p[c] += 2.f * a[j] - bf2f(z2[c]);
  }
}

// bf16 MFMA GEMM: C[m, c0+n] (+)= A[M,K](lda, bf16) * Bt[n][k] (ldb, bf16) + bias[n]
#define GBM 128
#define GBN 64
#define GBK 32
#define LPAD 8

__global__ __launch_bounds__(256) void gemm_bf16_kernel(
    const unsigned short* __restrict__ A, int lda,
    const unsigned short* __restrict__ Bt, int ldb,
    int M, int Nc, int K,
    const float* __restrict__ bias,
    unsigned short* __restrict__ Cb, float* __restrict__ Cf, int ldc, int c0,
    int accumulate) {
  __shared__ __align__(16) unsigned short As[GBM][GBK + LPAD];
  __shared__ __align__(16) unsigned short Bs[GBN][GBK + LPAD];
  int tid = threadIdx.x;
  int wave = tid >> 6, lane = tid & 63;
  int q = lane >> 4, mn = lane & 15;
  int row0 = blockIdx.y * GBM, col0 = blockIdx.x * GBN;
  floatx4 acc[2][4] = {};

  int sRow = tid >> 2;           // 0..63
  int sKoff = (tid & 3) * 8;     // 0,8,16,24

  for (int k0 = 0; k0 < K; k0 += GBK) {
#pragma unroll
    for (int p = 0; p < 2; p++) {
      int ar = sRow + p * 64;
      int gr = row0 + ar;
      uint4 av = make_uint4(0, 0, 0, 0);
      if (gr < M && (k0 + sKoff) < K)   // K multiple of 8 => full 8-elem group in-bounds
        av = *reinterpret_cast<const uint4*>(A + (size_t)gr * lda + k0 + sKoff);
      *reinterpret_cast<short8*>(&As[ar][sKoff]) = *reinterpret_cast<short8*>(&av);
    }
    {
      int gn = col0 + sRow;
      uint4 bv = make_uint4(0, 0, 0, 0);
      if (gn < Nc && (k0 + sKoff) < K)
        bv = *reinterpret_cast<const uint4*>(Bt + (size_t)gn * ldb + k0 + sKoff);
      *reinterpret_cast<short8*>(&Bs[sRow][sKoff]) = *reinterpret_cast<short8*>(&bv);
    }
    __syncthreads();

    short8 af[2], bf[4];
#pragma unroll
    for (int mi = 0; mi < 2; mi++)
      af[mi] = *reinterpret_cast<const short8*>(&As[wave * 32 + mi * 16 + mn][q * 8]);
#pragma unroll
    for (int ni = 0; ni < 4; ni++)
      bf[ni] = *reinterpret_cast<const short8*>(&Bs[ni * 16 + mn][q * 8]);
#pragma unroll
    for (int mi = 0; mi < 2; mi++)
#pragma unroll
      for (int ni = 0; ni < 4; ni++)
        acc[mi][ni] = __builtin_amdgcn_mfma_f32_16x16x32_bf16(af[mi], bf[ni], acc[mi][ni], 0, 0, 0);
    __syncthreads();
  }

  // epilogue: C/D layout col=lane&15, row=q*4+reg
#pragma unroll
  for (int mi = 0; mi < 2; mi++) {
#pragma unroll
    for (int ni = 0; ni < 4; ni++) {
      int gcol = col0 + ni * 16 + mn;
      if (gcol >= Nc) continue;
      float b = bias ? bias[gcol] : 0.f;
#pragma unroll
      for (int r = 0; r < 4; r++) {
        int grow = row0 + wave * 32 + mi * 16 + q * 4 + r;
        if (grow >= M) continue;
        float v = acc[mi][ni][r] + b;
        if (Cb) {
          Cb[(size_t)grow * ldc + c0 + gcol] = f2bf(v);
        } else {
          float* p = Cf + (size_t)grow * ldc + c0 + gcol;
          if (accumulate) v += *p;
          *p = v;
        }
      }
    }
  }
}

// BN stats over bf16 matrix (strided)
__global__ void bn_stats_bf16_kernel(const unsigned short* __restrict__ h, int ld, int C,
                                     int N, float* __restrict__ sums) {
  int c = blockIdx.x * blockDim.x + threadIdx.x;
  if (c >= C) return;
  int r0 = blockIdx.y * 256;
  int r1 = min(N, r0 + 256);
  float s = 0.f, s2 = 0.f;
  for (int r = r0; r < r1; r++) {
    float v = bf2f(h[(size_t)r * ld + c]);
    s += v; s2 += v * v;
  }
  atomicAdd(&sums[c], s);
  atomicAdd(&sums[C + c], s2);
}

__global__ void scsh_kernel(const float* __restrict__ sums, const float* __restrict__ g,
                            const float* __restrict__ beta, float invN, int C,
                            float* __restrict__ scSh) {
  int c = blockIdx.x * blockDim.x + threadIdx.x;
  if (c >= C) return;
  float mu = sums[c] * invN;
  float var = sums[C + c] * invN - mu * mu;
  float s = rsqrtf(var + EPSB) * g[c];
  scSh[c] = s;
  scSh[C + c] = beta[c] - mu * s;
}

// BN apply (+optional relu) on bf16 matrix, 8 cols/thread
__global__ void bn_apply_bf16_kernel(unsigned short* __restrict__ h, int ld, int C8, int N,
                                     const float* __restrict__ scSh, int Cfull, int relu) {
  int idx = blockIdx.x * blockDim.x + threadIdx.x;
  if (idx >= N * C8) return;
  int row = idx / C8, c8 = idx - row * C8;
  unsigned short* p = h + (size_t)row * ld + c8 * 8;
  uint4 raw = *reinterpret_cast<uint4*>(p);
  float v[8];
  v[0] = bf2f((unsigned short)(raw.x & 0xffff)); v[1] = bf2f((unsigned short)(raw.x >> 16));
  v[2] = bf2f((unsigned short)(raw.y & 0xffff)); v[3] = bf2f((unsigned short)(raw.y >> 16));
  v[4] = bf2f((unsigned short)(raw.z & 0xffff)); v[5] = bf2f((unsigned short)(raw.z >> 16));
  v[6] = bf2f((unsigned short)(raw.w & 0xffff)); v[7] = bf2f((unsigned short)(raw.w >> 16));
#pragma unroll
  for (int j = 0; j < 8; j++) {
    int c = c8 * 8 + j;
    float o = v[j] * scSh[c] + scSh[Cfull + c];
    if (relu) o = fmaxf(o, 0.f);
    v[j] = o;
  }
  uint4 o;
  o.x = (unsigned int)f2bf(v[0]) | ((unsigned int)f2bf(v[1]) << 16);
  o.y = (unsigned int)f2bf(v[2]) | ((unsigned int)f2bf(v[3]) << 16);
  o.z = (unsigned int)f2bf(v[4]) | ((unsigned int)f2bf(v[5]) << 16);
  o.w = (unsigned int)f2bf(v[6]) | ((unsigned int)f2bf(v[7]) << 16);
  *reinterpret_cast<uint4*>(p) = o;
}

// fp32 BN pieces
__global__ void bn_stats_kernel(const float* __restrict__ h, int C, int N,
                                float* __restrict__ sums) {
  int c = blockIdx.x * blockDim.x + threadIdx.x;
  if (c >= C) return;
  int r0 = blockIdx.y * 256;
  int r1 = min(N, r0 + 256);
  float s = 0.f, s2 = 0.f;
  for (int r = r0; r < r1; r++) {
    float v = h[(size_t)r * C + c];
    s += v; s2 += v * v;
  }
  atomicAdd(&sums[c], s);
  atomicAdd(&sums[C + c], s2);
}

__global__ void bn_apply_kernel(float* __restrict__ h, int C, int N,
                                const float* __restrict__ sums, const float* __restrict__ g,
                                const float* __restrict__ beta, float invN, int relu) {
  int C4 = C >> 2;
  int c4 = blockIdx.x * blockDim.x + threadIdx.x;
  if (c4 >= C4) return;
  float sc[4], sh[4];
#pragma unroll
  for (int j = 0; j < 4; j++) {
    int c = c4 * 4 + j;
    float mu = sums[c] * invN;
    float var = sums[C + c] * invN - mu * mu;
    float s = rsqrtf(var + EPSB) * g[c];
    sc[j] = s; sh[j] = beta[c] - mu * s;
  }
  int r0 = blockIdx.y * 256, r1 = min(N, r0 + 256);
  for (int r = r0; r < r1; r++) {
    float4* p = reinterpret_cast<float4*>(h + (size_t)r * C) + c4;
    float4 v = *p;
    v.x = v.x * sc[0] + sh[0]; v.y = v.y * sc[1] + sh[1];
    v.z = v.z * sc[2] + sh[2]; v.w = v.w * sc[3] + sh[3];
    if (relu) {
      v.x = fmaxf(v.x, 0.f); v.y = fmaxf(v.y, 0.f);
      v.z = fmaxf(v.z, 0.f); v.w = fmaxf(v.w, 0.f);
    }
    *p = v;
  }
}

// ---------------- final: BN2-apply fused + linear + log_softmax ----------------

__global__ __launch_bounds__(256) void final_bn_kernel(const float* __restrict__ h2,
                                                       const float* __restrict__ scSh,
                                                       const float* __restrict__ Wl,
                                                       const float* __restrict__ bl,
                                                       float* __restrict__ out, int N) {
  __shared__ float Ws[3000];
  __shared__ float S[600];
  for (int i = threadIdx.x; i < 3000; i += 256) Ws[i] = Wl[i];
  for (int i = threadIdx.x; i < 600; i += 256) S[i] = scSh[i];
  __syncthreads();
  int r = blockIdx.x * blockDim.x + threadIdx.x;
  if (r >= N) return;
  float acc[10];
#pragma unroll
  for (int c = 0; c < 10; c++) acc[c] = bl[c];
  const float* hr = h2 + (size_t)r * 300;
  for (int k = 0; k < 300; k++) {
    float x = hr[k] * S[k] + S[300 + k];
#pragma unroll
    for (int c = 0; c < 10; c++) acc[c] += x * Ws[k * 10 + c];
  }
  float mx = acc[0];
#pragma unroll
  for (int c = 1; c < 10; c++) mx = fmaxf(mx, acc[c]);
  float se = 0.f;
#pragma unroll
  for (int c = 0; c < 10; c++) se += expf(acc[c] - mx);
  float lz = mx + logf(se);
#pragma unroll
  for (int c = 0; c < 10; c++) out[(size_t)r * 10 + c] = acc[c] - lz;
}

// plain final for Plan B
__global__ __launch_bounds__(256) void final_kernel(const float* __restrict__ h2,
                                                    const float* __restrict__ Wl,
                                                    const float* __restrict__ bl,
                                                    float* __restrict__ out, int N) {
  __shared__ float Ws[3000];
  for (int i = threadIdx.x; i < 3000; i += 256) Ws[i] = Wl[i];
  __syncthreads();
  int r = blockIdx.x * blockDim.x + threadIdx.x;
  if (r >= N) return;
  float acc[10];
#pragma unroll
  for (int c = 0; c < 10; c++) acc[c] = bl[c];
  const float* hr = h2 + (size_t)r * 300;
  for (int k = 0; k < 300; k++) {
    float x = hr[k];
#pragma unroll
    for (int c = 0; c < 10; c++) acc[c] += x * Ws[k * 10 + c];
  }
  float mx = acc[0];
#pragma unroll
  for (int c = 1; c < 10; c++) mx = fmaxf(mx, acc[c]);
  float se = 0.f;
#pragma unroll
  for (int c = 0; c < 10; c++) se += expf(acc[c] - mx);
  float lz = mx + logf(se);
#pragma unroll
  for (int c = 0; c < 10; c++) out[(size_t)r * 10 + c] = acc[c] - lz;
}

// ================= PLAN B (fp32 fallback, known-good) =================

__global__ void prop_kernel(const float* __restrict__ src, int srcLd4, int D4,
                            const int* __restrict__ off, const int* __restrict__ eRow,
                            const float* __restrict__ eNorm,
                            float* __restrict__ dst, int dstLd4,
                            const float* __restrict__ sub, int subLd4, float scale) {
  int v = blockIdx.x;
  int f4 = threadIdx.x;
  if (f4 >= D4) return;
  int s = off[v], e = off[v + 1];
  float ax = 0.f, ay = 0.f, az = 0.f, aw = 0.f;
  for (int i = s; i < e; i++) {
    int r = eRow[i];
    float w = eNorm[i];
    const float4 hv = *reinterpret_cast<const float4*>(src + ((size_t)r * srcLd4 + f4) * 4);
    ax += w * hv.x; ay += w * hv.y; az += w * hv.z; aw += w * hv.w;
  }
  float4 o;
  if (sub) {
    const float4 sv = *reinterpret_cast<const float4*>(sub + ((size_t)v * subLd4 + f4) * 4);
    o.x = scale * ax - sv.x; o.y = scale * ay - sv.y;
    o.z = scale * az - sv.z; o.w = scale * aw - sv.w;
  } else {
    o.x = ax; o.y = ay; o.z = az; o.w = aw;
  }
  *reinterpret_cast<float4*>(dst + ((size_t)v * dstLd4 + f4) * 4) = o;
}

#define BM 64
#define BN 64
#define BK 16

__global__ __launch_bounds__(256) void gemm_kernel(
    const float* __restrict__ A, int lda,
    const float* __restrict__ B, int ldb,
    float* __restrict__ C, int ldc, int c0,
    int M, int Nc, int K,
    const float* __restrict__ bias, int accumulate) {
  __shared__ float As[BK][BM + 4];
  __shared__ float Bs[BK][BN + 4];
  int tid = threadIdx.x;
  int tx = tid & 15, ty = tid >> 4;
  int row0 = blockIdx.y * BM, col0 = blockIdx.x * BN;
  float acc[4][4] = {};
  int aM = tid >> 2;
  int aK = (tid & 3) << 2;
  int bK = tid >> 4;
  int bN = (tid & 15) << 2;
  for (int k0 = 0; k0 < K; k0 += BK) {
    float4 av = make_float4(0.f, 0.f, 0.f, 0.f);
    int ar = row0 + aM;
    if (ar < M && k0 + aK < K)
      av = *reinterpret_cast<const float4*>(A + (size_t)ar * lda + k0 + aK);
    As[aK + 0][aM] = av.x; As[aK + 1][aM] = av.y;
    As[aK + 2][aM] = av.z; As[aK + 3][aM] = av.w;
    float4 bv = make_float4(0.f, 0.f, 0.f, 0.f);
    int bc = col0 + bN;
    if (bc < Nc && k0 + bK < K)
      bv = *reinterpret_cast<const float4*>(B + (size_t)(k0 + bK) * ldb + bc);
    Bs[bK][bN + 0] = bv.x; Bs[bK][bN + 1] = bv.y;
    Bs[bK][bN + 2] = bv.z; Bs[bK][bN + 3] = bv.w;
    __syncthreads();
#pragma unroll
    for (int k = 0; k < BK; k++) {
      float a0 = As[k][ty * 4 + 0], a1 = As[k][ty * 4 + 1];
      float a2 = As[k][ty * 4 + 2], a3 = As[k][ty * 4 + 3];
      float b0 = Bs[k][tx * 4 + 0], b1 = Bs[k][tx * 4 + 1];
      float b2 = Bs[k][tx * 4 + 2], b3 = Bs[k][tx * 4 + 3];
      acc[0][0] += a0 * b0; acc[0][1] += a0 * b1; acc[0][2] += a0 * b2; acc[0][3] += a0 * b3;
      acc[1][0] += a1 * b0; acc[1][1] += a1 * b1; acc[1][2] += a1 * b2; acc[1][3] += a1 * b3;
      acc[2][0] += a2 * b0; acc[2][1] += a2 * b1; acc[2][2] += a2 * b2; acc[2][3] += a2 * b3;
      acc[3][0] += a3 * b0; acc[3][1] += a3 * b1; acc[3][2] += a3 * b2; acc[3][3] += a3 * b3;
    }
    __syncthreads();
  }
#pragma unroll
  for (int i = 0; i < 4; i++) {
    int r = row0 + ty * 4 + i;
    if (r >= M) continue;
#pragma unroll
    for (int j = 0; j < 4; j++) {
      int c = col0 + tx * 4 + j;
      if (c >= Nc) continue;
      float v = acc[i][j];
      if (bias) v += bias[c];
      float* p = C + (size_t)r * ldc + c0 + c;
      if (accumulate) *p += v; else *p = v;
    }
  }
}

// ---------------- launch ----------------

extern "C" void kernel_launch(void* const* d_in, const int* in_sizes, int n_in,
                              void* d_out, int out_size, void* d_ws, size_t ws_size,
                              hipStream_t stream) {
  const float* x   = (const float*)d_in[0];
  const int*   ei  = (const int*)d_in[1];
  const float* ew  = (const float*)d_in[2];
  const float* W1a = (const float*)d_in[3];
  const float* b1a = (const float*)d_in[4];
  const float* W1b = (const float*)d_in[5];
  const float* b1b = (const float*)d_in[6];
  const float* W1c = (const float*)d_in[7];
  const float* b1c = (const float*)d_in[8];
  const float* g1  = (const float*)d_in[9];
  const float* be1 = (const float*)d_in[10];
  const float* W2a = (const float*)d_in[11];
  const float* b2a = (const float*)d_in[12];
  const float* W2b = (const float*)d_in[13];
  const float* b2b = (const float*)d_in[14];
  const float* W2c = (const float*)d_in[15];
  const float* b2c = (const float*)d_in[16];
  const float* g2  = (const float*)d_in[17];
  const float* be2 = (const float*)d_in[18];
  const float* Wl  = (const float*)d_in[19];
  const float* bl  = (const float*)d_in[20];
  float* out = (float*)d_out;

  const int N = in_sizes[0] / 512;
  const int E = in_sizes[1] / 2;
  const int* row = ei;
  const int* col = ei + E;
  (void)n_in; (void)out_size;

  int eb = (E + 255) / 256;
  int nb = (N + 255) / 256;

  // ---- common prefix layout ----
  char* ws = (char*)d_ws;
  size_t o = 0;
  int*   eRow  = (int*)(ws + o);   o += (size_t)E * 4;
  float* eNorm = (float*)(ws + o); o += (size_t)E * 4;
  float* dis   = (float*)(ws + o); o += (size_t)N * 4;
  int*   cnt   = (int*)(ws + o);   o += (size_t)N * 4;
  int*   off   = (int*)(ws + o);   o += (size_t)(N + 4) * 4;
  int*   wptr  = (int*)(ws + o);   o += (size_t)N * 4;
  float* sums  = (float*)(ws + o); o += 2400 * 4;
  float* scSh  = (float*)(ws + o); o += 2400 * 4;
  float* bcat  = (float*)(ws + o); o += 304 * 4;
  o = (o + 255) & ~(size_t)255;
  size_t oCommon = o;

  // ---- plan A layout (~351 MB) ----
  size_t oA = oCommon;
  unsigned short* Bt1a = (unsigned short*)(ws + oA); oA += (size_t)400 * 512 * 2;
  unsigned short* Bt1b = (unsigned short*)(ws + oA); oA += (size_t)400 * 1024 * 2;
  unsigned short* Bt1c = (unsigned short*)(ws + oA); oA += (size_t)400 * 1536 * 2;
  unsigned short* Bt2cat0 = (unsigned short*)(ws + oA); oA += (size_t)300 * 1200 * 2;
  unsigned short* Bt2z    = (unsigned short*)(ws + oA); oA += (size_t)304 * 1200 * 2;
  oA = (oA + 255) & ~(size_t)255;
  unsigned short* h1n = (unsigned short*)(ws + oA); oA += (size_t)N * 1200 * 2;
  oA = (oA + 255) & ~(size_t)255;
  float* h2f = (float*)(ws + oA); oA += (size_t)N * 300 * 4;
  oA = (oA + 255) & ~(size_t)255;
  // region X: Xcat (N x 1536 bf16) in phase 1; Zcat (N x 304) + U1 (N x 104) in phase 2
  unsigned short* Xcat = (unsigned short*)(ws + oA); oA += (size_t)N * 1536 * 2;
  unsigned short* Zcat = Xcat;
  unsigned short* U1 = Xcat + (size_t)N * 304;

  bool planA = (ws_size >= oA);

  // ---- graph prep (both plans) ----
  hipMemsetAsync(dis, 0, (size_t)N * 4, stream);
  hipMemsetAsync(cnt, 0, (size_t)N * 4, stream);
  deg_kernel<<<eb, 256, 0, stream>>>(row, ew, dis, E);
  dis_kernel<<<nb, 256, 0, stream>>>(dis, N);
  count_kernel<<<eb, 256, 0, stream>>>(col, cnt, E);
  scan_kernel<<<1, 1024, 0, stream>>>(cnt, off, N);
  copy_kernel<<<nb, 256, 0, stream>>>(off, wptr, N);
  fill_kernel<<<eb, 256, 0, stream>>>(row, col, ew, dis, wptr, eRow, eNorm, E);

  if (planA) {
    // weight prep + x cast
    wprep_kernel<<<(400 * 512 + 255) / 256, 256, 0, stream>>>(W1a, Bt1a, 512, 400, 512, 0);
    wprep_kernel<<<(400 * 1024 + 255) / 256, 256, 0, stream>>>(W1b, Bt1b, 1024, 400, 1024, 0);
    wprep_kernel<<<(400 * 1536 + 255) / 256, 256, 0, stream>>>(W1c, Bt1c, 1536, 400, 1536, 0);
    // layer-2 weights: Bt2cat0 = [W2a|W2b0|W2c0]^T (300 x 1200)
    wprep_kernel<<<(100 * 1200 + 255) / 256, 256, 0, stream>>>(W2a, Bt2cat0, 1200, 100, 1200, 0);
    wprep_kernel<<<(100 * 1200 + 255) / 256, 256, 0, stream>>>(W2b, Bt2cat0, 1200, 100, 1200, 100);
    wprep_kernel<<<(100 * 1200 + 255) / 256, 256, 0, stream>>>(W2c, Bt2cat0, 1200, 100, 1200, 200);
    // Bt2z = [W2b1|W2c1|W2c2|0]^T (304 x 1200, rows 300..303 zero)
    hipMemsetAsync(Bt2z, 0, (size_t)304 * 1200 * 2, stream);
    wprep_kernel<<<(100 * 1200 + 255) / 256, 256, 0, stream>>>(W2b + 1200 * 100, Bt2z, 1200, 100, 1200, 0);
    wprep_kernel<<<(100 * 1200 + 255) / 256, 256, 0, stream>>>(W2c + 1200 * 100, Bt2z, 1200, 100, 1200, 100);
    wprep_kernel<<<(100 * 1200 + 255) / 256, 256, 0, stream>>>(W2c + 2 * 1200 * 100, Bt2z, 1200, 100, 1200, 200);
    bcat_kernel<<<1, 320, 0, stream>>>(b2a, b2b, b2c, bcat);
    cast_x_kernel<<<(N * 128 + 255) / 256, 256, 0, stream>>>(x, Xcat, N);

    // layer-1 props into Xcat: P1 = prop(x), P2 = 2*prop(P1) - x
    prop_bf16_kernel<<<N, 64, 0, stream>>>(Xcat, 1536, 64, off, eRow, eNorm,
                                           Xcat + 512, 1536, nullptr, 0, 1.f);
    prop_bf16_kernel<<<N, 64, 0, stream>>>(Xcat + 512, 1536, 64, off, eRow, eNorm,
                                           Xcat + 1024, 1536, Xcat, 1536, 2.f);

    // layer-1 GEMMs -> h1n (bf16, ld 1200)
    dim3 gA((400 + GBN - 1) / GBN, (N + GBM - 1) / GBM);
    gemm_bf16_kernel<<<gA, 256, 0, stream>>>(Xcat, 1536, Bt1a, 512, N, 400, 512,
                                             b1a, h1n, nullptr, 1200, 0, 0);
    gemm_bf16_kernel<<<gA, 256, 0, stream>>>(Xcat, 1536, Bt1b, 1024, N, 400, 1024,
                                             b1b, h1n, nullptr, 1200, 400, 0);
    gemm_bf16_kernel<<<gA, 256, 0, stream>>>(Xcat, 1536, Bt1c, 1536, N, 400, 1536,
                                             b1c, h1n, nullptr, 1200, 800, 0);

    // BN1 + ReLU on h1n
    hipMemsetAsync(sums, 0, 2400 * 4, stream);
    dim3 s1g((1200 + 255) / 256, (N + 255) / 256);
    bn_stats_bf16_kernel<<<s1g, 256, 0, stream>>>(h1n, 1200, 1200, N, sums);
    scsh_kernel<<<(1200 + 255) / 256, 256, 0, stream>>>(sums, g1, be1, 1.f / (float)N, 1200, scSh);
    bn_apply_bf16_kernel<<<((size_t)N * 150 + 255) / 256, 256, 0, stream>>>(
        h1n, 1200, 150, N, scSh, 1200, 1);

    // layer-2 GEMM 1: Y0 = h1n*[W2a|W2b0|W2c0] + bias -> h2f (fp32, 300 cols)
    dim3 gB0((300 + GBN - 1) / GBN, (N + GBM - 1) / GBM);
    gemm_bf16_kernel<<<gB0, 256, 0, stream>>>(h1n, 1200, Bt2cat0, 1200, N, 300, 1200,
                                              bcat, nullptr, h2f, 300, 0, 0);

    // layer-2 GEMM 2: Zcat = h1n*[W2b1|W2c1|W2c2|0] -> bf16 (304 cols, Xcat region)
    dim3 gBz((304 + GBN - 1) / GBN, (N + GBM - 1) / GBM);
    gemm_bf16_kernel<<<gBz, 256, 0, stream>>>(h1n, 1200, Bt2z, 1200, N, 304, 1200,
                                              nullptr, Zcat, nullptr, 304, 0, 0);

    // commuted props: h2f[:,100:300] += L*Z1 ; U1 = L*Z2
    prop_z_kernel<<<N, 64, 0, stream>>>(Zcat, off, eRow, eNorm, h2f, U1);
    // h2f[:,200:300] += 2*L*U1 - Z2
    prop_u_kernel<<<N, 64, 0, stream>>>(U1, off, eRow, eNorm, Zcat, h2f);

    // BN2 stats -> scSh; apply fused into final
    hipMemsetAsync(sums, 0, 2400 * 4, stream);
    dim3 s2g((300 + 255) / 256, (N + 255) / 256);
    bn_stats_kernel<<<s2g, 256, 0, stream>>>(h2f, 300, N, sums);
    scsh_kernel<<<(300 + 255) / 256, 256, 0, stream>>>(sums, g2, be2, 1.f / (float)N, 300, scSh);
    final_bn_kernel<<<nb, 256, 0, stream>>>(h2f, scSh, Wl, bl, out, N);
    return;
  }

  // ================= PLAN B (fp32 fallback) =================
  size_t oB = oCommon;
  float* h2 = (float*)(ws + oB); oB += (size_t)N * 300 * 4;
  oB = (oB + 255) & ~(size_t)255;
  float* h1 = (float*)(ws + oB); oB += (size_t)N * 1200 * 4;
  oB = (oB + 255) & ~(size_t)255;
  size_t avail = (ws_size > oB) ? (ws_size - oB) : 0;
  int C1 = 64;
  { const int opts[4] = {512, 256, 128, 64};
    for (int i = 0; i < 4; i++)
      if ((size_t)2 * N * opts[i] * 4 <= avail) { C1 = opts[i]; break; } }
  int C2 = 100;
  { const int opts[6] = {1200, 600, 400, 300, 200, 100};
    for (int i = 0; i < 6; i++)
      if ((size_t)2 * N * opts[i] * 4 <= avail) { C2 = opts[i]; break; } }
  int maxC = C1 > C2 ? C1 : C2;
  float* S1 = (float*)(ws + oB);
  float* S2 = S1 + (size_t)N * maxC;

  dim3 g1d((400 + BN - 1) / BN, (N + BM - 1) / BM);
  gemm_kernel<<<g1d, 256, 0, stream>>>(x, 512, W1a, 400, h1, 1200, 0,   N, 400, 512, b1a, 0);
  gemm_kernel<<<g1d, 256, 0, stream>>>(x, 512, W1b, 400, h1, 1200, 400, N, 400, 512, b1b, 0);
  gemm_kernel<<<g1d, 256, 0, stream>>>(x, 512, W1c, 400, h1, 1200, 800, N, 400, 512, b1c, 0);
  for (int c = 0; c < 512; c += C1) {
    int D4 = C1 / 4;
    int bt = ((D4 + 63) / 64) * 64;
    prop_kernel<<<N, bt, 0, stream>>>(x + c, 128, D4, off, eRow, eNorm, S1, D4, nullptr, 0, 1.f);
    gemm_kernel<<<g1d, 256, 0, stream>>>(S1, C1, W1b + (size_t)(512 + c) * 400, 400, h1, 1200, 400, N, 400, C1, nullptr, 1);
    gemm_kernel<<<g1d, 256, 0, stream>>>(S1, C1, W1c + (size_t)(512 + c) * 400, 400, h1, 1200, 800, N, 400, C1, nullptr, 1);
    prop_kernel<<<N, bt, 0, stream>>>(S1, D4, D4, off, eRow, eNorm, S2, D4, x + c, 128, 2.f);
    gemm_kernel<<<g1d, 256, 0, stream>>>(S2, C1, W1c + (size_t)(2 * 512 + c) * 400, 400, h1, 1200, 800, N, 400, C1, nullptr, 1);
  }

  hipMemsetAsync(sums, 0, 2400 * 4, stream);
  dim3 s1g((1200 + 255) / 256, (N + 255) / 256);
  bn_stats_kernel<<<s1g, 256, 0, stream>>>(h1, 1200, N, sums);
  dim3 a1g((300 + 63) / 64, (N + 255) / 256);
  bn_apply_kernel<<<a1g, 64, 0, stream>>>(h1, 1200, N, sums, g1, be1, 1.f / (float)N, 1);

  dim3 g2d((100 + BN - 1) / BN, (N + BM - 1) / BM);
  gemm_kernel<<<g2d, 256, 0, stream>>>(h1, 1200, W2a, 100, h2, 300, 0,   N, 100, 1200, b2a, 0);
  gemm_kernel<<<g2d, 256, 0, stream>>>(h1, 1200, W2b, 100, h2, 300, 100, N, 100, 1200, b2b, 0);
  gemm_kernel<<<g2d, 256, 0, stream>>>(h1, 1200, W2c, 100, h2, 300, 200, N, 100, 1200, b2c, 0);
  for (int c = 0; c < 1200; c += C2) {
    int D4 = C2 / 4;
    int bt = ((D4 + 63) / 64) * 64;
    prop_kernel<<<N, bt, 0, stream>>>(h1 + c, 300, D4, off, eRow, eNorm, S1, D4, nullptr, 0, 1.f);
    gemm_kernel<<<g2d, 256, 0, stream>>>(S1, C2, W2b + (size_t)(1200 + c) * 100, 100, h2, 300, 100, N, 100, C2, nullptr, 1);
    gemm_kernel<<<g2d, 256, 0, stream>>>(S1, C2, W2c + (size_t)(1200 + c) * 100, 100, h2, 300, 200, N, 100, C2, nullptr, 1);
    prop_kernel<<<N, bt, 0, stream>>>(S1, D4, D4, off, eRow, eNorm, S2, D4, h1 + c, 300, 2.f);
    gemm_kernel<<<g2d, 256, 0, stream>>>(S2, C2, W2c + (size_t)(2 * 1200 + c) * 100, 100, h2, 300, 200, N, 100, C2, nullptr, 1);
  }

  hipMemsetAsync(sums, 0, 2400 * 4, stream);
  dim3 s2g((300 + 255) / 256, (N + 255) / 256);
  bn_stats_kernel<<<s2g, 256, 0, stream>>>(h2, 300, N, sums);
  dim3 a2g((75 + 63) / 64, (N + 255) / 256);
  bn_apply_kernel<<<a2g, 64, 0, stream>>>(h2, 300, N, sums, g2, be2, 1.f / (float)N, 0);

  final_kernel<<<nb, 256, 0, stream>>>(h2, Wl, bl, out, N);
}

// Round 7
// 2353.360 us; speedup vs baseline: 1.4485x; 1.0149x over previous
//
#include <hip/hip_runtime.h>
#include <math.h>

#define EPSB 1e-5f

typedef __attribute__((ext_vector_type(8))) short short8;
typedef __attribute__((ext_vector_type(4))) float floatx4;

__device__ inline float bf2f(unsigned short h) {
  union { unsigned int u; float f; } v; v.u = ((unsigned int)h) << 16; return v.f;
}
__device__ inline unsigned short f2bf(float f) {
  union { float f; unsigned int u; } v; v.f = f;
  unsigned int r = v.u + 0x7fffu + ((v.u >> 16) & 1u);  // RNE
  return (unsigned short)(r >> 16);
}

// ---------------- graph prep (shared by both plans) ----------------

__global__ void deg_kernel(const int* __restrict__ row, const float* __restrict__ ew,
                           float* __restrict__ deg, int E) {
  int e = blockIdx.x * blockDim.x + threadIdx.x;
  if (e < E) atomicAdd(&deg[row[e]], ew[e]);
}

__global__ void dis_kernel(float* deg, int n) {
  int i = blockIdx.x * blockDim.x + threadIdx.x;
  if (i < n) { float d = deg[i]; deg[i] = d > 0.f ? rsqrtf(d) : 0.f; }
}

__global__ void count_kernel(const int* __restrict__ col, int* __restrict__ cnt, int E) {
  int e = blockIdx.x * blockDim.x + threadIdx.x;
  if (e < E) atomicAdd(&cnt[col[e]], 1);
}

__global__ __launch_bounds__(1024) void scan_kernel(const int* __restrict__ cnt,
                                                    int* __restrict__ off, int n) {
  __shared__ int buf[1024];
  __shared__ int carry;
  int tid = threadIdx.x;
  if (tid == 0) carry = 0;
  __syncthreads();
  for (int base = 0; base < n; base += 1024) {
    int idx = base + tid;
    int v = (idx < n) ? cnt[idx] : 0;
    buf[tid] = v;
    __syncthreads();
    for (int s = 1; s < 1024; s <<= 1) {
      int t = (tid >= s) ? buf[tid - s] : 0;
      __syncthreads();
      if (tid >= s) buf[tid] += t;
      __syncthreads();
    }
    int total = buf[1023];
    if (idx < n) off[idx] = carry + buf[tid] - v;  // exclusive
    __syncthreads();
    if (tid == 0) carry += total;
    __syncthreads();
  }
  if (tid == 0) off[n] = carry;
}

__global__ void copy_kernel(const int* __restrict__ src, int* __restrict__ dst, int n) {
  int i = blockIdx.x * blockDim.x + threadIdx.x;
  if (i < n) dst[i] = src[i];
}

__global__ void fill_kernel(const int* __restrict__ row, const int* __restrict__ col,
                            const float* __restrict__ ew, const float* __restrict__ dis,
                            int* __restrict__ wptr,
                            int* __restrict__ eRow, float* __restrict__ eNorm, int E) {
  int e = blockIdx.x * blockDim.x + threadIdx.x;
  if (e < E) {
    int r = row[e], c = col[e];
    int p = atomicAdd(&wptr[c], 1);
    eRow[p] = r;
    eNorm[p] = -dis[r] * ew[e] * dis[c];
  }
}

// ================= PLAN A (bf16 + MFMA) =================

// cast x (N x 512 fp32) into Xcat cols [0,512) (ld 1536, bf16)
__global__ void cast_x_kernel(const float* __restrict__ x, unsigned short* __restrict__ xb,
                              int N) {
  int idx = blockIdx.x * blockDim.x + threadIdx.x;
  if (idx >= N * 128) return;
  int row = idx >> 7, c4 = idx & 127;
  float4 v = *reinterpret_cast<const float4*>(x + (size_t)row * 512 + c4 * 4);
  union { unsigned int u[2]; } p;
  p.u[0] = (unsigned int)f2bf(v.x) | ((unsigned int)f2bf(v.y) << 16);
  p.u[1] = (unsigned int)f2bf(v.z) | ((unsigned int)f2bf(v.w) << 16);
  *reinterpret_cast<uint2*>(xb + (size_t)row * 1536 + c4 * 4) = make_uint2(p.u[0], p.u[1]);
}

// transpose+cast weights: W[k][n] fp32 (n fastest) -> Bt[rowOff+n][k] bf16 (ld ldBt)
__global__ void wprep_kernel(const float* __restrict__ W, unsigned short* __restrict__ Bt,
                             int Ktot, int Nout, int ldBt, int rowOff) {
  int idx = blockIdx.x * blockDim.x + threadIdx.x;
  if (idx >= Ktot * Nout) return;
  int k = idx / Nout, n = idx - k * Nout;
  Bt[(size_t)(rowOff + n) * ldBt + k] = f2bf(W[idx]);
}

__global__ void bcat_kernel(const float* __restrict__ a, const float* __restrict__ b,
                            const float* __restrict__ c, float* __restrict__ dst) {
  int i = threadIdx.x;
  if (i < 100) dst[i] = a[i];
  else if (i < 200) dst[i] = b[i - 100];
  else if (i < 300) dst[i] = c[i - 200];
}

__device__ inline void acc8(float* a, uint4 g, float w) {
  a[0] += w * bf2f((unsigned short)(g.x & 0xffff));
  a[1] += w * bf2f((unsigned short)(g.x >> 16));
  a[2] += w * bf2f((unsigned short)(g.y & 0xffff));
  a[3] += w * bf2f((unsigned short)(g.y >> 16));
  a[4] += w * bf2f((unsigned short)(g.z & 0xffff));
  a[5] += w * bf2f((unsigned short)(g.z >> 16));
  a[6] += w * bf2f((unsigned short)(g.w & 0xffff));
  a[7] += w * bf2f((unsigned short)(g.w >> 16));
}

// ---- XCD-affine chunked layer-1 prop ----
// 8 col-chunks of 64; chunk = blockIdx.x & 7 rides round-robin XCD dispatch so
// each XCD's gathers hit a ~6 MB L2-resident source slice.
// Block: 256 thr = 8 nodes x (4 edge-slots x 8 col-threads of 16B).
// dst[v, dstCol+co] = scale * sum_e w_e src[row_e, srcCol+co] - sub[v, subCol+co]
__global__ __launch_bounds__(256) void prop_chunk_kernel(
    unsigned short* __restrict__ base, int ld,
    int srcCol, int dstCol, int subCol,    // subCol < 0 => no sub
    const int* __restrict__ off, const int* __restrict__ eRow,
    const float* __restrict__ eNorm, float scale, int N) {
  int chunk = blockIdx.x & 7;
  int g = blockIdx.x >> 3;
  int tid = threadIdx.x;
  int slot = (tid >> 3) & 3;
  int c8 = tid & 7;
  int v = g * 8 + (tid >> 5);
  bool valid = v < N;
  int vv = valid ? v : N - 1;
  int co = chunk * 64 + c8 * 8;
  const unsigned short* src = base + srcCol + co;
  int s = off[vv], e = off[vv + 1];
  float a[8] = {};
  for (int i = s + slot; i < e; i += 4) {
    int r = eRow[i];
    float w = eNorm[i];
    uint4 gg = *reinterpret_cast<const uint4*>(src + (size_t)r * ld);
    acc8(a, gg, w);
  }
  // reduce across the 4 edge-slots (lane bits 3,4 — stays in each node's 32 lanes)
#pragma unroll
  for (int j = 0; j < 8; j++) {
    a[j] += __shfl_xor(a[j], 8);
    a[j] += __shfl_xor(a[j], 16);
  }
  if (slot != 0 || !valid) return;
  if (subCol >= 0) {
    uint4 sv = *reinterpret_cast<const uint4*>(base + subCol + co + (size_t)v * ld);
    a[0] = scale * a[0] - bf2f((unsigned short)(sv.x & 0xffff));
    a[1] = scale * a[1] - bf2f((unsigned short)(sv.x >> 16));
    a[2] = scale * a[2] - bf2f((unsigned short)(sv.y & 0xffff));
    a[3] = scale * a[3] - bf2f((unsigned short)(sv.y >> 16));
    a[4] = scale * a[4] - bf2f((unsigned short)(sv.z & 0xffff));
    a[5] = scale * a[5] - bf2f((unsigned short)(sv.z >> 16));
    a[6] = scale * a[6] - bf2f((unsigned short)(sv.w & 0xffff));
    a[7] = scale * a[7] - bf2f((unsigned short)(sv.w >> 16));
  }
  uint4 o;
  o.x = (unsigned int)f2bf(a[0]) | ((unsigned int)f2bf(a[1]) << 16);
  o.y = (unsigned int)f2bf(a[2]) | ((unsigned int)f2bf(a[3]) << 16);
  o.z = (unsigned int)f2bf(a[4]) | ((unsigned int)f2bf(a[5]) << 16);
  o.w = (unsigned int)f2bf(a[6]) | ((unsigned int)f2bf(a[7]) << 16);
  *reinterpret_cast<uint4*>(base + dstCol + co + (size_t)v * ld) = o;
}

// ---- commuted layer-2 props ----
__global__ void prop_z_kernel(const unsigned short* __restrict__ Zcat,
                              const int* __restrict__ off, const int* __restrict__ eRow,
                              const float* __restrict__ eNorm,
                              float* __restrict__ h2f, unsigned short* __restrict__ U1) {
  int v = blockIdx.x;
  int f8 = threadIdx.x;
  if (f8 >= 38) return;
  int s = off[v], e = off[v + 1];
  float a[8] = {};
  for (int i = s; i < e; i++) {
    int r = eRow[i];
    float w = eNorm[i];
    uint4 raw = *reinterpret_cast<const uint4*>(Zcat + (size_t)r * 304 + f8 * 8);
    acc8(a, raw, w);
  }
  if (f8 < 25) {
    float* p = h2f + (size_t)v * 300 + 100 + f8 * 8;
#pragma unroll
    for (int j = 0; j < 8; j++) p[j] += a[j];
  } else {
    uint4 o;
    o.x = (unsigned int)f2bf(a[0]) | ((unsigned int)f2bf(a[1]) << 16);
    o.y = (unsigned int)f2bf(a[2]) | ((unsigned int)f2bf(a[3]) << 16);
    o.z = (unsigned int)f2bf(a[4]) | ((unsigned int)f2bf(a[5]) << 16);
    o.w = (unsigned int)f2bf(a[6]) | ((unsigned int)f2bf(a[7]) << 16);
    *reinterpret_cast<uint4*>(U1 + (size_t)v * 104 + (f8 - 25) * 8) = o;
  }
}

__global__ void prop_u_kernel(const unsigned short* __restrict__ U1,
                              const int* __restrict__ off, const int* __restrict__ eRow,
                              const float* __restrict__ eNorm,
                              const unsigned short* __restrict__ Zcat,
                              float* __restrict__ h2f) {
  int v = blockIdx.x;
  int f8 = threadIdx.x;
  if (f8 >= 13) return;
  int s = off[v], e = off[v + 1];
  float a[8] = {};
  for (int i = s; i < e; i++) {
    int r = eRow[i];
    float w = eNorm[i];
    uint4 raw = *reinterpret_cast<const uint4*>(U1 + (size_t)r * 104 + f8 * 8);
    acc8(a, raw, w);
  }
  const unsigned short* z2 = Zcat + (size_t)v * 304 + 200;
  float* p = h2f + (size_t)v * 300 + 200;
#pragma unroll
  for (int j = 0; j < 8; j++) {
    int c = f8 * 8 + j;
    if (c < 100) p[c] += 2.f * a[j] - bf2f(z2[c]);
  }
}

// bf16 MFMA GEMM: C[m, c0+n] (+)= A[M,K](lda, bf16) * Bt[n][k] (ldb, bf16) + bias[n]
#define GBM 128
#define GBN 64
#define GBK 32
#define LPAD 8

__global__ __launch_bounds__(256) void gemm_bf16_kernel(
    const unsigned short* __restrict__ A, int lda,
    const unsigned short* __restrict__ Bt, int ldb,
    int M, int Nc, int K,
    const float* __restrict__ bias,
    unsigned short* __restrict__ Cb, float* __restrict__ Cf, int ldc, int c0,
    int accumulate) {
  __shared__ __align__(16) unsigned short As[GBM][GBK + LPAD];
  __shared__ __align__(16) unsigned short Bs[GBN][GBK + LPAD];
  int tid = threadIdx.x;
  int wave = tid >> 6, lane = tid & 63;
  int q = lane >> 4, mn = lane & 15;
  int row0 = blockIdx.y * GBM, col0 = blockIdx.x * GBN;
  floatx4 acc[2][4] = {};

  int sRow = tid >> 2;           // 0..63
  int sKoff = (tid & 3) * 8;     // 0,8,16,24

  for (int k0 = 0; k0 < K; k0 += GBK) {
#pragma unroll
    for (int p = 0; p < 2; p++) {
      int ar = sRow + p * 64;
      int gr = row0 + ar;
      uint4 av = make_uint4(0, 0, 0, 0);
      if (gr < M && (k0 + sKoff) < K)
        av = *reinterpret_cast<const uint4*>(A + (size_t)gr * lda + k0 + sKoff);
      *reinterpret_cast<short8*>(&As[ar][sKoff]) = *reinterpret_cast<short8*>(&av);
    }
    {
      int gn = col0 + sRow;
      uint4 bv = make_uint4(0, 0, 0, 0);
      if (gn < Nc && (k0 + sKoff) < K)
        bv = *reinterpret_cast<const uint4*>(Bt + (size_t)gn * ldb + k0 + sKoff);
      *reinterpret_cast<short8*>(&Bs[sRow][sKoff]) = *reinterpret_cast<short8*>(&bv);
    }
    __syncthreads();

    short8 af[2], bf[4];
#pragma unroll
    for (int mi = 0; mi < 2; mi++)
      af[mi] = *reinterpret_cast<const short8*>(&As[wave * 32 + mi * 16 + mn][q * 8]);
#pragma unroll
    for (int ni = 0; ni < 4; ni++)
      bf[ni] = *reinterpret_cast<const short8*>(&Bs[ni * 16 + mn][q * 8]);
#pragma unroll
    for (int mi = 0; mi < 2; mi++)
#pragma unroll
      for (int ni = 0; ni < 4; ni++)
        acc[mi][ni] = __builtin_amdgcn_mfma_f32_16x16x32_bf16(af[mi], bf[ni], acc[mi][ni], 0, 0, 0);
    __syncthreads();
  }

  // epilogue: C/D layout col=lane&15, row=q*4+reg
#pragma unroll
  for (int mi = 0; mi < 2; mi++) {
#pragma unroll
    for (int ni = 0; ni < 4; ni++) {
      int gcol = col0 + ni * 16 + mn;
      if (gcol >= Nc) continue;
      float b = bias ? bias[gcol] : 0.f;
#pragma unroll
      for (int r = 0; r < 4; r++) {
        int grow = row0 + wave * 32 + mi * 16 + q * 4 + r;
        if (grow >= M) continue;
        float v = acc[mi][ni][r] + b;
        if (Cb) {
          Cb[(size_t)grow * ldc + c0 + gcol] = f2bf(v);
        } else {
          float* p = Cf + (size_t)grow * ldc + c0 + gcol;
          if (accumulate) v += *p;
          *p = v;
        }
      }
    }
  }
}

// BN stats over bf16 matrix (strided)
__global__ void bn_stats_bf16_kernel(const unsigned short* __restrict__ h, int ld, int C,
                                     int N, float* __restrict__ sums) {
  int c = blockIdx.x * blockDim.x + threadIdx.x;
  if (c >= C) return;
  int r0 = blockIdx.y * 256;
  int r1 = min(N, r0 + 256);
  float s = 0.f, s2 = 0.f;
  for (int r = r0; r < r1; r++) {
    float v = bf2f(h[(size_t)r * ld + c]);
    s += v; s2 += v * v;
  }
  atomicAdd(&sums[c], s);
  atomicAdd(&sums[C + c], s2);
}

__global__ void scsh_kernel(const float* __restrict__ sums, const float* __restrict__ g,
                            const float* __restrict__ beta, float invN, int C,
                            float* __restrict__ scSh) {
  int c = blockIdx.x * blockDim.x + threadIdx.x;
  if (c >= C) return;
  float mu = sums[c] * invN;
  float var = sums[C + c] * invN - mu * mu;
  float s = rsqrtf(var + EPSB) * g[c];
  scSh[c] = s;
  scSh[C + c] = beta[c] - mu * s;
}

// BN apply (+optional relu) on bf16 matrix, 8 cols/thread
__global__ void bn_apply_bf16_kernel(unsigned short* __restrict__ h, int ld, int C8, int N,
                                     const float* __restrict__ scSh, int Cfull, int relu) {
  int idx = blockIdx.x * blockDim.x + threadIdx.x;
  if (idx >= N * C8) return;
  int row = idx / C8, c8 = idx - row * C8;
  unsigned short* p = h + (size_t)row * ld + c8 * 8;
  uint4 raw = *reinterpret_cast<uint4*>(p);
  float v[8];
  v[0] = bf2f((unsigned short)(raw.x & 0xffff)); v[1] = bf2f((unsigned short)(raw.x >> 16));
  v[2] = bf2f((unsigned short)(raw.y & 0xffff)); v[3] = bf2f((unsigned short)(raw.y >> 16));
  v[4] = bf2f((unsigned short)(raw.z & 0xffff)); v[5] = bf2f((unsigned short)(raw.z >> 16));
  v[6] = bf2f((unsigned short)(raw.w & 0xffff)); v[7] = bf2f((unsigned short)(raw.w >> 16));
#pragma unroll
  for (int j = 0; j < 8; j++) {
    int c = c8 * 8 + j;
    float o = v[j] * scSh[c] + scSh[Cfull + c];
    if (relu) o = fmaxf(o, 0.f);
    v[j] = o;
  }
  uint4 o;
  o.x = (unsigned int)f2bf(v[0]) | ((unsigned int)f2bf(v[1]) << 16);
  o.y = (unsigned int)f2bf(v[2]) | ((unsigned int)f2bf(v[3]) << 16);
  o.z = (unsigned int)f2bf(v[4]) | ((unsigned int)f2bf(v[5]) << 16);
  o.w = (unsigned int)f2bf(v[6]) | ((unsigned int)f2bf(v[7]) << 16);
  *reinterpret_cast<uint4*>(p) = o;
}

// fp32 BN pieces
__global__ void bn_stats_kernel(const float* __restrict__ h, int C, int N,
                                float* __restrict__ sums) {
  int c = blockIdx.x * blockDim.x + threadIdx.x;
  if (c >= C) return;
  int r0 = blockIdx.y * 256;
  int r1 = min(N, r0 + 256);
  float s = 0.f, s2 = 0.f;
  for (int r = r0; r < r1; r++) {
    float v = h[(size_t)r * C + c];
    s += v; s2 += v * v;
  }
  atomicAdd(&sums[c], s);
  atomicAdd(&sums[C + c], s2);
}

__global__ void bn_apply_kernel(float* __restrict__ h, int C, int N,
                                const float* __restrict__ sums, const float* __restrict__ g,
                                const float* __restrict__ beta, float invN, int relu) {
  int C4 = C >> 2;
  int c4 = blockIdx.x * blockDim.x + threadIdx.x;
  if (c4 >= C4) return;
  float sc[4], sh[4];
#pragma unroll
  for (int j = 0; j < 4; j++) {
    int c = c4 * 4 + j;
    float mu = sums[c] * invN;
    float var = sums[C + c] * invN - mu * mu;
    float s = rsqrtf(var + EPSB) * g[c];
    sc[j] = s; sh[j] = beta[c] - mu * s;
  }
  int r0 = blockIdx.y * 256, r1 = min(N, r0 + 256);
  for (int r = r0; r < r1; r++) {
    float4* p = reinterpret_cast<float4*>(h + (size_t)r * C) + c4;
    float4 v = *p;
    v.x = v.x * sc[0] + sh[0]; v.y = v.y * sc[1] + sh[1];
    v.z = v.z * sc[2] + sh[2]; v.w = v.w * sc[3] + sh[3];
    if (relu) {
      v.x = fmaxf(v.x, 0.f); v.y = fmaxf(v.y, 0.f);
      v.z = fmaxf(v.z, 0.f); v.w = fmaxf(v.w, 0.f);
    }
    *p = v;
  }
}

// ---------------- final: BN2-apply fused + linear + log_softmax ----------------

__global__ __launch_bounds__(256) void final_bn_kernel(const float* __restrict__ h2,
                                                       const float* __restrict__ scSh,
                                                       const float* __restrict__ Wl,
                                                       const float* __restrict__ bl,
                                                       float* __restrict__ out, int N) {
  __shared__ float Ws[3000];
  __shared__ float S[600];
  for (int i = threadIdx.x; i < 3000; i += 256) Ws[i] = Wl[i];
  for (int i = threadIdx.x; i < 600; i += 256) S[i] = scSh[i];
  __syncthreads();
  int r = blockIdx.x * blockDim.x + threadIdx.x;
  if (r >= N) return;
  float acc[10];
#pragma unroll
  for (int c = 0; c < 10; c++) acc[c] = bl[c];
  const float* hr = h2 + (size_t)r * 300;
  for (int k = 0; k < 300; k++) {
    float x = hr[k] * S[k] + S[300 + k];
#pragma unroll
    for (int c = 0; c < 10; c++) acc[c] += x * Ws[k * 10 + c];
  }
  float mx = acc[0];
#pragma unroll
  for (int c = 1; c < 10; c++) mx = fmaxf(mx, acc[c]);
  float se = 0.f;
#pragma unroll
  for (int c = 0; c < 10; c++) se += expf(acc[c] - mx);
  float lz = mx + logf(se);
#pragma unroll
  for (int c = 0; c < 10; c++) out[(size_t)r * 10 + c] = acc[c] - lz;
}

// plain final for Plan B
__global__ __launch_bounds__(256) void final_kernel(const float* __restrict__ h2,
                                                    const float* __restrict__ Wl,
                                                    const float* __restrict__ bl,
                                                    float* __restrict__ out, int N) {
  __shared__ float Ws[3000];
  for (int i = threadIdx.x; i < 3000; i += 256) Ws[i] = Wl[i];
  __syncthreads();
  int r = blockIdx.x * blockDim.x + threadIdx.x;
  if (r >= N) return;
  float acc[10];
#pragma unroll
  for (int c = 0; c < 10; c++) acc[c] = bl[c];
  const float* hr = h2 + (size_t)r * 300;
  for (int k = 0; k < 300; k++) {
    float x = hr[k];
#pragma unroll
    for (int c = 0; c < 10; c++) acc[c] += x * Ws[k * 10 + c];
  }
  float mx = acc[0];
#pragma unroll
  for (int c = 1; c < 10; c++) mx = fmaxf(mx, acc[c]);
  float se = 0.f;
#pragma unroll
  for (int c = 0; c < 10; c++) se += expf(acc[c] - mx);
  float lz = mx + logf(se);
#pragma unroll
  for (int c = 0; c < 10; c++) out[(size_t)r * 10 + c] = acc[c] - lz;
}

// ================= PLAN B (fp32 fallback, known-good) =================

__global__ void prop_kernel(const float* __restrict__ src, int srcLd4, int D4,
                            const int* __restrict__ off, const int* __restrict__ eRow,
                            const float* __restrict__ eNorm,
                            float* __restrict__ dst, int dstLd4,
                            const float* __restrict__ sub, int subLd4, float scale) {
  int v = blockIdx.x;
  int f4 = threadIdx.x;
  if (f4 >= D4) return;
  int s = off[v], e = off[v + 1];
  float ax = 0.f, ay = 0.f, az = 0.f, aw = 0.f;
  for (int i = s; i < e; i++) {
    int r = eRow[i];
    float w = eNorm[i];
    const float4 hv = *reinterpret_cast<const float4*>(src + ((size_t)r * srcLd4 + f4) * 4);
    ax += w * hv.x; ay += w * hv.y; az += w * hv.z; aw += w * hv.w;
  }
  float4 o;
  if (sub) {
    const float4 sv = *reinterpret_cast<const float4*>(sub + ((size_t)v * subLd4 + f4) * 4);
    o.x = scale * ax - sv.x; o.y = scale * ay - sv.y;
    o.z = scale * az - sv.z; o.w = scale * aw - sv.w;
  } else {
    o.x = ax; o.y = ay; o.z = az; o.w = aw;
  }
  *reinterpret_cast<float4*>(dst + ((size_t)v * dstLd4 + f4) * 4) = o;
}

#define BM 64
#define BN 64
#define BK 16

__global__ __launch_bounds__(256) void gemm_kernel(
    const float* __restrict__ A, int lda,
    const float* __restrict__ B, int ldb,
    float* __restrict__ C, int ldc, int c0,
    int M, int Nc, int K,
    const float* __restrict__ bias, int accumulate) {
  __shared__ float As[BK][BM + 4];
  __shared__ float Bs[BK][BN + 4];
  int tid = threadIdx.x;
  int tx = tid & 15, ty = tid >> 4;
  int row0 = blockIdx.y * BM, col0 = blockIdx.x * BN;
  float acc[4][4] = {};
  int aM = tid >> 2;
  int aK = (tid & 3) << 2;
  int bK = tid >> 4;
  int bN = (tid & 15) << 2;
  for (int k0 = 0; k0 < K; k0 += BK) {
    float4 av = make_float4(0.f, 0.f, 0.f, 0.f);
    int ar = row0 + aM;
    if (ar < M && k0 + aK < K)
      av = *reinterpret_cast<const float4*>(A + (size_t)ar * lda + k0 + aK);
    As[aK + 0][aM] = av.x; As[aK + 1][aM] = av.y;
    As[aK + 2][aM] = av.z; As[aK + 3][aM] = av.w;
    float4 bv = make_float4(0.f, 0.f, 0.f, 0.f);
    int bc = col0 + bN;
    if (bc < Nc && k0 + bK < K)
      bv = *reinterpret_cast<const float4*>(B + (size_t)(k0 + bK) * ldb + bc);
    Bs[bK][bN + 0] = bv.x; Bs[bK][bN + 1] = bv.y;
    Bs[bK][bN + 2] = bv.z; Bs[bK][bN + 3] = bv.w;
    __syncthreads();
#pragma unroll
    for (int k = 0; k < BK; k++) {
      float a0 = As[k][ty * 4 + 0], a1 = As[k][ty * 4 + 1];
      float a2 = As[k][ty * 4 + 2], a3 = As[k][ty * 4 + 3];
      float b0 = Bs[k][tx * 4 + 0], b1 = Bs[k][tx * 4 + 1];
      float b2 = Bs[k][tx * 4 + 2], b3 = Bs[k][tx * 4 + 3];
      acc[0][0] += a0 * b0; acc[0][1] += a0 * b1; acc[0][2] += a0 * b2; acc[0][3] += a0 * b3;
      acc[1][0] += a1 * b0; acc[1][1] += a1 * b1; acc[1][2] += a1 * b2; acc[1][3] += a1 * b3;
      acc[2][0] += a2 * b0; acc[2][1] += a2 * b1; acc[2][2] += a2 * b2; acc[2][3] += a2 * b3;
      acc[3][0] += a3 * b0; acc[3][1] += a3 * b1; acc[3][2] += a3 * b2; acc[3][3] += a3 * b3;
    }
    __syncthreads();
  }
#pragma unroll
  for (int i = 0; i < 4; i++) {
    int r = row0 + ty * 4 + i;
    if (r >= M) continue;
#pragma unroll
    for (int j = 0; j < 4; j++) {
      int c = col0 + tx * 4 + j;
      if (c >= Nc) continue;
      float v = acc[i][j];
      if (bias) v += bias[c];
      float* p = C + (size_t)r * ldc + c0 + c;
      if (accumulate) *p += v; else *p = v;
    }
  }
}

// ---------------- launch ----------------

extern "C" void kernel_launch(void* const* d_in, const int* in_sizes, int n_in,
                              void* d_out, int out_size, void* d_ws, size_t ws_size,
                              hipStream_t stream) {
  const float* x   = (const float*)d_in[0];
  const int*   ei  = (const int*)d_in[1];
  const float* ew  = (const float*)d_in[2];
  const float* W1a = (const float*)d_in[3];
  const float* b1a = (const float*)d_in[4];
  const float* W1b = (const float*)d_in[5];
  const float* b1b = (const float*)d_in[6];
  const float* W1c = (const float*)d_in[7];
  const float* b1c = (const float*)d_in[8];
  const float* g1  = (const float*)d_in[9];
  const float* be1 = (const float*)d_in[10];
  const float* W2a = (const float*)d_in[11];
  const float* b2a = (const float*)d_in[12];
  const float* W2b = (const float*)d_in[13];
  const float* b2b = (const float*)d_in[14];
  const float* W2c = (const float*)d_in[15];
  const float* b2c = (const float*)d_in[16];
  const float* g2  = (const float*)d_in[17];
  const float* be2 = (const float*)d_in[18];
  const float* Wl  = (const float*)d_in[19];
  const float* bl  = (const float*)d_in[20];
  float* out = (float*)d_out;

  const int N = in_sizes[0] / 512;
  const int E = in_sizes[1] / 2;
  const int* row = ei;
  const int* col = ei + E;
  (void)n_in; (void)out_size;

  int eb = (E + 255) / 256;
  int nb = (N + 255) / 256;

  // ---- common prefix layout ----
  char* ws = (char*)d_ws;
  size_t o = 0;
  int*   eRow  = (int*)(ws + o);   o += (size_t)E * 4;
  float* eNorm = (float*)(ws + o); o += (size_t)E * 4;
  float* dis   = (float*)(ws + o); o += (size_t)N * 4;
  int*   cnt   = (int*)(ws + o);   o += (size_t)N * 4;
  int*   off   = (int*)(ws + o);   o += (size_t)(N + 4) * 4;
  int*   wptr  = (int*)(ws + o);   o += (size_t)N * 4;
  float* sums  = (float*)(ws + o); o += 2400 * 4;
  float* scSh  = (float*)(ws + o); o += 2400 * 4;
  float* bcat  = (float*)(ws + o); o += 304 * 4;
  o = (o + 255) & ~(size_t)255;
  size_t oCommon = o;

  // ---- plan A layout (~351 MB) ----
  size_t oA = oCommon;
  unsigned short* Bt1a = (unsigned short*)(ws + oA); oA += (size_t)400 * 512 * 2;
  unsigned short* Bt1b = (unsigned short*)(ws + oA); oA += (size_t)400 * 1024 * 2;
  unsigned short* Bt1c = (unsigned short*)(ws + oA); oA += (size_t)400 * 1536 * 2;
  unsigned short* Bt2cat0 = (unsigned short*)(ws + oA); oA += (size_t)300 * 1200 * 2;
  unsigned short* Bt2z    = (unsigned short*)(ws + oA); oA += (size_t)304 * 1200 * 2;
  oA = (oA + 255) & ~(size_t)255;
  unsigned short* h1n = (unsigned short*)(ws + oA); oA += (size_t)N * 1200 * 2;
  oA = (oA + 255) & ~(size_t)255;
  float* h2f = (float*)(ws + oA); oA += (size_t)N * 300 * 4;
  oA = (oA + 255) & ~(size_t)255;
  // region X: Xcat (N x 1536 bf16) in phase 1; Zcat (N x 304) + U1 (N x 104) in phase 2
  unsigned short* Xcat = (unsigned short*)(ws + oA); oA += (size_t)N * 1536 * 2;
  unsigned short* Zcat = Xcat;
  unsigned short* U1 = Xcat + (size_t)N * 304;

  bool planA = (ws_size >= oA);

  // ---- graph prep (both plans) ----
  hipMemsetAsync(dis, 0, (size_t)N * 4, stream);
  hipMemsetAsync(cnt, 0, (size_t)N * 4, stream);
  deg_kernel<<<eb, 256, 0, stream>>>(row, ew, dis, E);
  dis_kernel<<<nb, 256, 0, stream>>>(dis, N);
  count_kernel<<<eb, 256, 0, stream>>>(col, cnt, E);
  scan_kernel<<<1, 1024, 0, stream>>>(cnt, off, N);
  copy_kernel<<<nb, 256, 0, stream>>>(off, wptr, N);
  fill_kernel<<<eb, 256, 0, stream>>>(row, col, ew, dis, wptr, eRow, eNorm, E);

  if (planA) {
    // weight prep + x cast
    wprep_kernel<<<(400 * 512 + 255) / 256, 256, 0, stream>>>(W1a, Bt1a, 512, 400, 512, 0);
    wprep_kernel<<<(400 * 1024 + 255) / 256, 256, 0, stream>>>(W1b, Bt1b, 1024, 400, 1024, 0);
    wprep_kernel<<<(400 * 1536 + 255) / 256, 256, 0, stream>>>(W1c, Bt1c, 1536, 400, 1536, 0);
    wprep_kernel<<<(100 * 1200 + 255) / 256, 256, 0, stream>>>(W2a, Bt2cat0, 1200, 100, 1200, 0);
    wprep_kernel<<<(100 * 1200 + 255) / 256, 256, 0, stream>>>(W2b, Bt2cat0, 1200, 100, 1200, 100);
    wprep_kernel<<<(100 * 1200 + 255) / 256, 256, 0, stream>>>(W2c, Bt2cat0, 1200, 100, 1200, 200);
    hipMemsetAsync(Bt2z, 0, (size_t)304 * 1200 * 2, stream);
    wprep_kernel<<<(100 * 1200 + 255) / 256, 256, 0, stream>>>(W2b + 1200 * 100, Bt2z, 1200, 100, 1200, 0);
    wprep_kernel<<<(100 * 1200 + 255) / 256, 256, 0, stream>>>(W2c + 1200 * 100, Bt2z, 1200, 100, 1200, 100);
    wprep_kernel<<<(100 * 1200 + 255) / 256, 256, 0, stream>>>(W2c + 2 * 1200 * 100, Bt2z, 1200, 100, 1200, 200);
    bcat_kernel<<<1, 320, 0, stream>>>(b2a, b2b, b2c, bcat);
    cast_x_kernel<<<(N * 128 + 255) / 256, 256, 0, stream>>>(x, Xcat, N);

    // layer-1 props (XCD-affine chunked): P1 = L x ; P2 = 2 L P1 - x
    int gridP = ((N + 7) / 8) * 8;
    prop_chunk_kernel<<<gridP, 256, 0, stream>>>(Xcat, 1536, 0, 512, -1,
                                                 off, eRow, eNorm, 1.f, N);
    prop_chunk_kernel<<<gridP, 256, 0, stream>>>(Xcat, 1536, 512, 1024, 0,
                                                 off, eRow, eNorm, 2.f, N);

    // layer-1 GEMMs -> h1n (bf16, ld 1200)
    dim3 gA((400 + GBN - 1) / GBN, (N + GBM - 1) / GBM);
    gemm_bf16_kernel<<<gA, 256, 0, stream>>>(Xcat, 1536, Bt1a, 512, N, 400, 512,
                                             b1a, h1n, nullptr, 1200, 0, 0);
    gemm_bf16_kernel<<<gA, 256, 0, stream>>>(Xcat, 1536, Bt1b, 1024, N, 400, 1024,
                                             b1b, h1n, nullptr, 1200, 400, 0);
    gemm_bf16_kernel<<<gA, 256, 0, stream>>>(Xcat, 1536, Bt1c, 1536, N, 400, 1536,
                                             b1c, h1n, nullptr, 1200, 800, 0);

    // BN1 + ReLU on h1n
    hipMemsetAsync(sums, 0, 2400 * 4, stream);
    dim3 s1g((1200 + 255) / 256, (N + 255) / 256);
    bn_stats_bf16_kernel<<<s1g, 256, 0, stream>>>(h1n, 1200, 1200, N, sums);
    scsh_kernel<<<(1200 + 255) / 256, 256, 0, stream>>>(sums, g1, be1, 1.f / (float)N, 1200, scSh);
    bn_apply_bf16_kernel<<<((size_t)N * 150 + 255) / 256, 256, 0, stream>>>(
        h1n, 1200, 150, N, scSh, 1200, 1);

    // layer-2 GEMM 1: h2f = h1n*[W2a|W2b0|W2c0] + bias (fp32, 300 cols)
    dim3 gB0((300 + GBN - 1) / GBN, (N + GBM - 1) / GBM);
    gemm_bf16_kernel<<<gB0, 256, 0, stream>>>(h1n, 1200, Bt2cat0, 1200, N, 300, 1200,
                                              bcat, nullptr, h2f, 300, 0, 0);

    // layer-2 GEMM 2: Zcat = h1n*[W2b1|W2c1|W2c2|0] -> bf16 (304 cols)
    dim3 gBz((304 + GBN - 1) / GBN, (N + GBM - 1) / GBM);
    gemm_bf16_kernel<<<gBz, 256, 0, stream>>>(h1n, 1200, Bt2z, 1200, N, 304, 1200,
                                              nullptr, Zcat, nullptr, 304, 0, 0);

    // commuted props
    prop_z_kernel<<<N, 64, 0, stream>>>(Zcat, off, eRow, eNorm, h2f, U1);
    prop_u_kernel<<<N, 64, 0, stream>>>(U1, off, eRow, eNorm, Zcat, h2f);

    // BN2 stats -> scSh; apply fused into final
    hipMemsetAsync(sums, 0, 2400 * 4, stream);
    dim3 s2g((300 + 255) / 256, (N + 255) / 256);
    bn_stats_kernel<<<s2g, 256, 0, stream>>>(h2f, 300, N, sums);
    scsh_kernel<<<(300 + 255) / 256, 256, 0, stream>>>(sums, g2, be2, 1.f / (float)N, 300, scSh);
    final_bn_kernel<<<nb, 256, 0, stream>>>(h2f, scSh, Wl, bl, out, N);
    return;
  }

  // ================= PLAN B (fp32 fallback) =================
  size_t oB = oCommon;
  float* h2 = (float*)(ws + oB); oB += (size_t)N * 300 * 4;
  oB = (oB + 255) & ~(size_t)255;
  float* h1 = (float*)(ws + oB); oB += (size_t)N * 1200 * 4;
  oB = (oB + 255) & ~(size_t)255;
  size_t avail = (ws_size > oB) ? (ws_size - oB) : 0;
  int C1 = 64;
  { const int opts[4] = {512, 256, 128, 64};
    for (int i = 0; i < 4; i++)
      if ((size_t)2 * N * opts[i] * 4 <= avail) { C1 = opts[i]; break; } }
  int C2 = 100;
  { const int opts[6] = {1200, 600, 400, 300, 200, 100};
    for (int i = 0; i < 6; i++)
      if ((size_t)2 * N * opts[i] * 4 <= avail) { C2 = opts[i]; break; } }
  int maxC = C1 > C2 ? C1 : C2;
  float* S1 = (float*)(ws + oB);
  float* S2 = S1 + (size_t)N * maxC;

  dim3 g1d((400 + BN - 1) / BN, (N + BM - 1) / BM);
  gemm_kernel<<<g1d, 256, 0, stream>>>(x, 512, W1a, 400, h1, 1200, 0,   N, 400, 512, b1a, 0);
  gemm_kernel<<<g1d, 256, 0, stream>>>(x, 512, W1b, 400, h1, 1200, 400, N, 400, 512, b1b, 0);
  gemm_kernel<<<g1d, 256, 0, stream>>>(x, 512, W1c, 400, h1, 1200, 800, N, 400, 512, b1c, 0);
  for (int c = 0; c < 512; c += C1) {
    int D4 = C1 / 4;
    int bt = ((D4 + 63) / 64) * 64;
    prop_kernel<<<N, bt, 0, stream>>>(x + c, 128, D4, off, eRow, eNorm, S1, D4, nullptr, 0, 1.f);
    gemm_kernel<<<g1d, 256, 0, stream>>>(S1, C1, W1b + (size_t)(512 + c) * 400, 400, h1, 1200, 400, N, 400, C1, nullptr, 1);
    gemm_kernel<<<g1d, 256, 0, stream>>>(S1, C1, W1c + (size_t)(512 + c) * 400, 400, h1, 1200, 800, N, 400, C1, nullptr, 1);
    prop_kernel<<<N, bt, 0, stream>>>(S1, D4, D4, off, eRow, eNorm, S2, D4, x + c, 128, 2.f);
    gemm_kernel<<<g1d, 256, 0, stream>>>(S2, C1, W1c + (size_t)(2 * 512 + c) * 400, 400, h1, 1200, 800, N, 400, C1, nullptr, 1);
  }

  hipMemsetAsync(sums, 0, 2400 * 4, stream);
  dim3 s1g((1200 + 255) / 256, (N + 255) / 256);
  bn_stats_kernel<<<s1g, 256, 0, stream>>>(h1, 1200, N, sums);
  dim3 a1g((300 + 63) / 64, (N + 255) / 256);
  bn_apply_kernel<<<a1g, 64, 0, stream>>>(h1, 1200, N, sums, g1, be1, 1.f / (float)N, 1);

  dim3 g2d((100 + BN - 1) / BN, (N + BM - 1) / BM);
  gemm_kernel<<<g2d, 256, 0, stream>>>(h1, 1200, W2a, 100, h2, 300, 0,   N, 100, 1200, b2a, 0);
  gemm_kernel<<<g2d, 256, 0, stream>>>(h1, 1200, W2b, 100, h2, 300, 100, N, 100, 1200, b2b, 0);
  gemm_kernel<<<g2d, 256, 0, stream>>>(h1, 1200, W2c, 100, h2, 300, 200, N, 100, 1200, b2c, 0);
  for (int c = 0; c < 1200; c += C2) {
    int D4 = C2 / 4;
    int bt = ((D4 + 63) / 64) * 64;
    prop_kernel<<<N, bt, 0, stream>>>(h1 + c, 300, D4, off, eRow, eNorm, S1, D4, nullptr, 0, 1.f);
    gemm_kernel<<<g2d, 256, 0, stream>>>(S1, C2, W2b + (size_t)(1200 + c) * 100, 100, h2, 300, 100, N, 100, C2, nullptr, 1);
    gemm_kernel<<<g2d, 256, 0, stream>>>(S1, C2, W2c + (size_t)(1200 + c) * 100, 100, h2, 300, 200, N, 100, C2, nullptr, 1);
    prop_kernel<<<N, bt, 0, stream>>>(S1, D4, D4, off, eRow, eNorm, S2, D4, h1 + c, 300, 2.f);
    gemm_kernel<<<g2d, 256, 0, stream>>>(S2, C2, W2c + (size_t)(2 * 1200 + c) * 100, 100, h2, 300, 200, N, 100, C2, nullptr, 1);
  }

  hipMemsetAsync(sums, 0, 2400 * 4, stream);
  dim3 s2g((300 + 255) / 256, (N + 255) / 256);
  bn_stats_kernel<<<s2g, 256, 0, stream>>>(h2, 300, N, sums);
  dim3 a2g((75 + 63) / 64, (N + 255) / 256);
  bn_apply_kernel<<<a2g, 64, 0, stream>>>(h2, 300, N, sums, g2, be2, 1.f / (float)N, 0);

  final_kernel<<<nb, 256, 0, stream>>>(h2, Wl, bl, out, N);
}